// Round 3
// baseline (1100.828 us; speedup 1.0000x reference)
//
#include <hip/hip_runtime.h>
#include <hip/hip_bf16.h>
#include <cstdint>
#include <cstddef>

#define B_   2
#define N_   65536
#define GXv  480
#define GYv  360
#define NHv  32
#define HWv  (GXv*GYv)          // 172800

// round-to-nearest-even f32 -> bf16
__device__ __forceinline__ unsigned short f2bf(float f) {
    unsigned u = __float_as_uint(f);
    u += 0x7FFFu + ((u >> 16) & 1u);
    return (unsigned short)(u >> 16);
}

// ---------------- init / zero ----------------
__global__ void k_init_head(int* head) {
    int i = blockIdx.x * 256 + threadIdx.x;
    if (i < B_ * HWv) head[i] = -1;
}
// d_out is FLOAT32: B*NH*HW floats = 44.2 MB = 2764800 uint4
__global__ void k_zero_out(uint4* out) {
    int i = blockIdx.x * 256 + threadIdx.x;
    if (i < (B_ * NHv * HWv * 4) / 16) out[i] = make_uint4(0, 0, 0, 0);
}

// ---------------- voxel bucketing (linked lists) ----------------
// Chain order is atomic-nondeterministic, but max-pooling is commutative and
// no voxel here reaches MAX_PT=256 points (65536 pts over 129600 voxels,
// Poisson max ~8), so keep==all-true — output is deterministic.
__global__ void k_chain(const int* __restrict__ xy, int* head, int* nxt) {
    int i = blockIdx.x * 256 + threadIdx.x;
    if (i >= B_ * N_) return;
    int b = i >> 16;                       // N_ = 65536
    int x = xy[2 * i], y = xy[2 * i + 1];
    nxt[i] = atomicExch(&head[b * HWv + x * GYv + y], i);
}

// ---------------- fused point MLP ----------------
// 32-point tiles, 256 threads = 8 point-blocks(x4 pts) x 32 channel-blocks.
// Static LDS = (64+128+256)*36 floats = 64512 B  (<= 64 KB limit).
__global__ __launch_bounds__(256) void k_mlp(
        const float* __restrict__ pt_fea,
        const float* __restrict__ s0v, const float* __restrict__ t0v,
        const float* __restrict__ s1v, const float* __restrict__ t1v,
        const float* __restrict__ s2v, const float* __restrict__ t2v,
        const float* __restrict__ s3v, const float* __restrict__ t3v,
        const float* __restrict__ W1, const float* __restrict__ b1,
        const float* __restrict__ W2, const float* __restrict__ b2,
        const float* __restrict__ W3, const float* __restrict__ b3,
        const float* __restrict__ W4, const float* __restrict__ b4,
        unsigned short* __restrict__ x4out)
{
    __shared__ __align__(16) float x1s[64 * 36];
    __shared__ __align__(16) float x2s[128 * 36];
    __shared__ __align__(16) float x3s[256 * 36];
    float* x0s = x2s;                  // alias: 9*32 floats, dead before x2 written

    int tid = threadIdx.x;
    int bid = blockIdx.x;              // 4096 blocks: 2048 per batch
    int b   = bid >> 11;
    int n0  = (bid & 2047) << 5;       // 32-point tile
    const float* fea = pt_fea + ((size_t)(b * N_ + n0)) * 9;

    for (int idx = tid; idx < 288; idx += 256) {
        int p = idx / 9, k = idx - p * 9;
        x0s[k * 32 + p] = fea[p * 9 + k] * s0v[k] + t0v[k];
    }
    __syncthreads();

    int pb = tid & 7, cb = tid >> 3;   // pts pb*4..+3, channel-block cb

    { // L1: 9 -> 64  (2 channels/thread)
        float acc[4][2] = {};
        #pragma unroll
        for (int k = 0; k < 9; ++k) {
            float a[4];
            *reinterpret_cast<float4*>(a) =
                *reinterpret_cast<const float4*>(&x0s[k * 32 + pb * 4]);
            float w0 = W1[k * 64 + cb * 2];
            float w1 = W1[k * 64 + cb * 2 + 1];
            #pragma unroll
            for (int i = 0; i < 4; ++i) {
                acc[i][0] = fmaf(a[i], w0, acc[i][0]);
                acc[i][1] = fmaf(a[i], w1, acc[i][1]);
            }
        }
        #pragma unroll
        for (int j = 0; j < 2; ++j) {
            int c = cb * 2 + j;
            float bb = b1[c], s = s1v[c], t = t1v[c];
            float v[4];
            #pragma unroll
            for (int i = 0; i < 4; ++i)
                v[i] = fmaxf(fmaf(acc[i][j] + bb, s, t), 0.f);
            *reinterpret_cast<float4*>(&x1s[c * 36 + pb * 4]) =
                *reinterpret_cast<float4*>(v);
        }
    }
    __syncthreads();

    { // L2: 64 -> 128  (4 channels/thread)
        float acc[4][4] = {};
        #pragma unroll 4
        for (int k = 0; k < 64; ++k) {
            float a[4], w[4];
            *reinterpret_cast<float4*>(a) =
                *reinterpret_cast<const float4*>(&x1s[k * 36 + pb * 4]);
            *reinterpret_cast<float4*>(w) =
                *reinterpret_cast<const float4*>(&W2[k * 128 + cb * 4]);
            #pragma unroll
            for (int i = 0; i < 4; ++i)
                #pragma unroll
                for (int j = 0; j < 4; ++j)
                    acc[i][j] = fmaf(a[i], w[j], acc[i][j]);
        }
        #pragma unroll
        for (int j = 0; j < 4; ++j) {
            int c = cb * 4 + j;
            float bb = b2[c], s = s2v[c], t = t2v[c];
            float v[4];
            #pragma unroll
            for (int i = 0; i < 4; ++i)
                v[i] = fmaxf(fmaf(acc[i][j] + bb, s, t), 0.f);
            *reinterpret_cast<float4*>(&x2s[c * 36 + pb * 4]) =
                *reinterpret_cast<float4*>(v);
        }
    }
    __syncthreads();

    { // L3: 128 -> 256  (8 channels/thread)
        float acc[4][8] = {};
        #pragma unroll 4
        for (int k = 0; k < 128; ++k) {
            float a[4];
            *reinterpret_cast<float4*>(a) =
                *reinterpret_cast<const float4*>(&x2s[k * 36 + pb * 4]);
            #pragma unroll
            for (int h = 0; h < 2; ++h) {
                float w[4];
                *reinterpret_cast<float4*>(w) =
                    *reinterpret_cast<const float4*>(&W3[k * 256 + cb * 8 + h * 4]);
                #pragma unroll
                for (int i = 0; i < 4; ++i)
                    #pragma unroll
                    for (int j = 0; j < 4; ++j)
                        acc[i][h * 4 + j] = fmaf(a[i], w[j], acc[i][h * 4 + j]);
            }
        }
        #pragma unroll
        for (int h = 0; h < 2; ++h)
            #pragma unroll
            for (int j = 0; j < 4; ++j) {
                int c = cb * 8 + h * 4 + j;
                float bb = b3[c], s = s3v[c], t = t3v[c];
                float v[4];
                #pragma unroll
                for (int i = 0; i < 4; ++i)
                    v[i] = fmaxf(fmaf(acc[i][h * 4 + j] + bb, s, t), 0.f);
                *reinterpret_cast<float4*>(&x3s[c * 36 + pb * 4]) =
                    *reinterpret_cast<float4*>(v);
            }
    }
    __syncthreads();

    { // L4: 256 -> 512  (16 channels/thread), +bias only, bf16 out
        float acc[4][16] = {};
        #pragma unroll 2
        for (int k = 0; k < 256; ++k) {
            float a[4];
            *reinterpret_cast<float4*>(a) =
                *reinterpret_cast<const float4*>(&x3s[k * 36 + pb * 4]);
            #pragma unroll
            for (int h = 0; h < 4; ++h) {
                float w[4];
                *reinterpret_cast<float4*>(w) =
                    *reinterpret_cast<const float4*>(&W4[k * 512 + cb * 16 + h * 4]);
                #pragma unroll
                for (int i = 0; i < 4; ++i)
                    #pragma unroll
                    for (int j = 0; j < 4; ++j)
                        acc[i][h * 4 + j] = fmaf(a[i], w[j], acc[i][h * 4 + j]);
            }
        }
        #pragma unroll
        for (int h = 0; h < 4; ++h) {
            int c = cb * 16 + h * 4;
            #pragma unroll
            for (int i = 0; i < 4; ++i) {
                int n = n0 + pb * 4 + i;
                unsigned short o[4];
                #pragma unroll
                for (int j = 0; j < 4; ++j)
                    o[j] = f2bf(acc[i][h * 4 + j] + b4[c + j]);
                *reinterpret_cast<uint2*>(&x4out[((size_t)(b * N_ + n)) * 512 + c]) =
                    *reinterpret_cast<uint2*>(o);
            }
        }
    }
}

// ---------------- per-voxel max-pool + compression ----------------
__global__ __launch_bounds__(256) void k_pool(
        const int* __restrict__ head, const int* __restrict__ nxt,
        const unsigned short* __restrict__ x4,
        const float* __restrict__ Wc, const float* __restrict__ bcv,
        float* __restrict__ out)
{
    __shared__ float mxsh[8][512];
    __shared__ float compsh[8][33];
    __shared__ int   gh[8];
    int tid = threadIdx.x;

    #pragma unroll 1
    for (int it = 0; it < 20; ++it) {
        int gbase = (it * 2160 + blockIdx.x) * 8;   // 2160*8*20 = 345600 = B*HW
        {   // phase 1: chain walk + segment max (32 lanes x 16 channels each)
            int g = tid >> 5, l = tid & 31;
            int gid = gbase + g;
            int h = head[gid];
            if (l == 0) gh[g] = h;
            if (h >= 0) {
                float mx[16];
                #pragma unroll
                for (int j = 0; j < 16; ++j) mx[j] = -3.0e38f;
                int cur = h;
                while (cur >= 0) {
                    const unsigned short* row = x4 + (size_t)cur * 512 + l * 16;
                    uint4 r0 = *reinterpret_cast<const uint4*>(row);
                    uint4 r1 = *reinterpret_cast<const uint4*>(row + 8);
                    unsigned rr[8] = {r0.x, r0.y, r0.z, r0.w, r1.x, r1.y, r1.z, r1.w};
                    #pragma unroll
                    for (int q = 0; q < 8; ++q) {
                        mx[2*q]   = fmaxf(mx[2*q],   __uint_as_float((rr[q] & 0xFFFFu) << 16));
                        mx[2*q+1] = fmaxf(mx[2*q+1], __uint_as_float(rr[q] & 0xFFFF0000u));
                    }
                    cur = nxt[cur];
                }
                #pragma unroll
                for (int j = 0; j < 16; ++j) mxsh[g][l * 16 + j] = mx[j];
            }
        }
        __syncthreads();
        {   // phase 2: comp[j] = relu(mx . Wc[:,j] + bc[j])
            int g = tid >> 5, j = tid & 31;
            if (gh[g] >= 0) {
                float s = bcv[j];
                #pragma unroll 8
                for (int c = 0; c < 512; ++c)
                    s = fmaf(mxsh[g][c], Wc[c * 32 + j], s);
                compsh[g][j] = fmaxf(s, 0.f);
            }
        }
        __syncthreads();
        {   // phase 3: transposed scatter (float32 output), 8 voxels x 32 ch
            int gi = tid & 7, j = tid >> 3;
            if (gh[gi] >= 0) {
                int gid = gbase + gi;
                int b = gid / HWv, v = gid - b * HWv;
                int x = v / GYv, y = v - x * GYv;
                out[(((size_t)b * NHv + j) * GXv + x) * GYv + y] = compsh[gi][j];
            }
        }
        __syncthreads();
    }
}

extern "C" void kernel_launch(void* const* d_in, const int* in_sizes, int n_in,
                              void* d_out, int out_size, void* d_ws, size_t ws_size,
                              hipStream_t stream) {
    const float* pt_fea = (const float*)d_in[0];
    const int*   xy     = (const int*)d_in[1];
    const float* s0v = (const float*)d_in[2];  const float* t0v = (const float*)d_in[3];
    const float* s1v = (const float*)d_in[4];  const float* t1v = (const float*)d_in[5];
    const float* s2v = (const float*)d_in[6];  const float* t2v = (const float*)d_in[7];
    const float* s3v = (const float*)d_in[8];  const float* t3v = (const float*)d_in[9];
    const float* W1  = (const float*)d_in[10]; const float* b1  = (const float*)d_in[11];
    const float* W2  = (const float*)d_in[12]; const float* b2  = (const float*)d_in[13];
    const float* W3  = (const float*)d_in[14]; const float* b3  = (const float*)d_in[15];
    const float* W4  = (const float*)d_in[16]; const float* b4  = (const float*)d_in[17];
    const float* Wc  = (const float*)d_in[18]; const float* bc  = (const float*)d_in[19];

    // workspace layout: x4 (bf16, 134MB) | head (1.35MB) | next (0.5MB)
    char* ws = (char*)d_ws;
    unsigned short* x4 = (unsigned short*)ws;
    int* head = (int*)(ws + (size_t)B_ * N_ * 512 * 2);
    int* nxt  = (int*)(ws + (size_t)B_ * N_ * 512 * 2 + (size_t)B_ * HWv * 4);

    hipLaunchKernelGGL(k_init_head, dim3(1350),  dim3(256), 0, stream, head);
    hipLaunchKernelGGL(k_zero_out,  dim3(10800), dim3(256), 0, stream, (uint4*)d_out);
    hipLaunchKernelGGL(k_chain,     dim3(512),   dim3(256), 0, stream, xy, head, nxt);
    hipLaunchKernelGGL(k_mlp,       dim3(4096),  dim3(256), 0, stream,
        pt_fea, s0v, t0v, s1v, t1v, s2v, t2v, s3v, t3v,
        W1, b1, W2, b2, W3, b3, W4, b4, x4);
    hipLaunchKernelGGL(k_pool,      dim3(2160),  dim3(256), 0, stream,
        head, nxt, x4, Wc, bc, (float*)d_out);
}

// Round 4
// 735.318 us; speedup vs baseline: 1.4971x; 1.4971x over previous
//
#include <hip/hip_runtime.h>
#include <hip/hip_bf16.h>
#include <cstdint>
#include <cstddef>

#define B_   2
#define N_   65536
#define GXv  480
#define GYv  360
#define NHv  32
#define HWv  (GXv*GYv)          // 172800

typedef __attribute__((ext_vector_type(8))) short short8;
typedef __attribute__((ext_vector_type(4))) float floatx4;

// round-to-nearest-even f32 -> bf16
__device__ __forceinline__ unsigned short f2bf(float f) {
    unsigned u = __float_as_uint(f);
    u += 0x7FFFu + ((u >> 16) & 1u);
    return (unsigned short)(u >> 16);
}

// ---------------- init / zero ----------------
__global__ void k_init_head(int* head) {
    int i = blockIdx.x * 256 + threadIdx.x;
    if (i < B_ * HWv) head[i] = -1;
}
// d_out is FLOAT32: B*NH*HW floats = 44.2 MB = 2764800 uint4
__global__ void k_zero_out(uint4* out) {
    int i = blockIdx.x * 256 + threadIdx.x;
    if (i < (B_ * NHv * HWv * 4) / 16) out[i] = make_uint4(0, 0, 0, 0);
}

// ---------------- voxel bucketing (linked lists) ----------------
__global__ void k_chain(const int* __restrict__ xy, int* head, int* nxt) {
    int i = blockIdx.x * 256 + threadIdx.x;
    if (i >= B_ * N_) return;
    int b = i >> 16;                       // N_ = 65536
    int x = xy[2 * i], y = xy[2 * i + 1];
    nxt[i] = atomicExch(&head[b * HWv + x * GYv + y], i);
}

// ---------------- W4 -> bf16, B-fragment-linear ----------------
// dst[(((nh*8+kc)*16+nt)*64+l)*8+j] = bf16(W4[k][n]),
//   k = kc*32 + (l>>4)*8 + j,  n = nh*256 + nt*16 + (l&15)
__global__ void k_cvtW4(const float* __restrict__ W4, unsigned short* __restrict__ dst) {
    int d = blockIdx.x * 256 + threadIdx.x;          // 16384 threads
    if (d >= 16384) return;
    int l  = d & 63;
    int nt = (d >> 6) & 15;
    int kc = (d >> 10) & 7;
    int nh = d >> 13;
    int n  = nh * 256 + nt * 16 + (l & 15);
    int k0 = kc * 32 + (l >> 4) * 8;
    unsigned short o[8];
    #pragma unroll
    for (int j = 0; j < 8; ++j) o[j] = f2bf(W4[(size_t)(k0 + j) * 512 + n]);
    *reinterpret_cast<uint4*>(dst + (size_t)d * 8) = *reinterpret_cast<const uint4*>(o);
}

// ---------------- fused point MLP ----------------
// 32-pt tiles, 256 thr. L1-L3 vector f32; L4 = bf16 MFMA 16x16x32.
// LDS arena 51200 B:
//   [0,32768)      x3A (A-fragment-linear bf16)  -- also aliases x1,x0 early
//   [0,9216)       x1 [64][36] f32   (dead before x3A written)
//   [9216,10368)   x0 [9][32] f32    (dead before x3A written)
//   [32768,51200)  x2 [128][36] f32  (dead before w4c staged)
//   [32768,49152)  w4c 16KB W4-chunk / epilogue repack area
__global__ __launch_bounds__(256) void k_mlp(
        const float* __restrict__ pt_fea,
        const float* __restrict__ s0v, const float* __restrict__ t0v,
        const float* __restrict__ s1v, const float* __restrict__ t1v,
        const float* __restrict__ s2v, const float* __restrict__ t2v,
        const float* __restrict__ s3v, const float* __restrict__ t3v,
        const float* __restrict__ W1, const float* __restrict__ b1,
        const float* __restrict__ W2, const float* __restrict__ b2,
        const float* __restrict__ W3, const float* __restrict__ b3,
        const unsigned short* __restrict__ W4f, const float* __restrict__ b4,
        unsigned short* __restrict__ x4out)
{
    __shared__ __align__(16) char smem[51200];
    float* x1s = reinterpret_cast<float*>(smem);                 // [64][36]
    float* x0s = reinterpret_cast<float*>(smem + 9216);          // [9][32]
    float* x2s = reinterpret_cast<float*>(smem + 32768);         // [128][36]
    unsigned short* x3A = reinterpret_cast<unsigned short*>(smem);        // 32KB
    unsigned short* w4c = reinterpret_cast<unsigned short*>(smem + 32768);// 16KB

    int tid = threadIdx.x;
    int bid = blockIdx.x;              // 4096 blocks: 2048 per batch
    int b   = bid >> 11;
    int n0  = (bid & 2047) << 5;       // 32-point tile
    const float* fea = pt_fea + ((size_t)(b * N_ + n0)) * 9;

    for (int idx = tid; idx < 288; idx += 256) {
        int p = idx / 9, k = idx - p * 9;
        x0s[k * 32 + p] = fea[p * 9 + k] * s0v[k] + t0v[k];
    }
    __syncthreads();

    int pb = tid & 7, cb = tid >> 3;   // pts pb*4..+3, channel-block cb

    { // L1: 9 -> 64  (2 channels/thread)
        float acc[4][2] = {};
        #pragma unroll
        for (int k = 0; k < 9; ++k) {
            float a[4];
            *reinterpret_cast<float4*>(a) =
                *reinterpret_cast<const float4*>(&x0s[k * 32 + pb * 4]);
            float w0 = W1[k * 64 + cb * 2];
            float w1 = W1[k * 64 + cb * 2 + 1];
            #pragma unroll
            for (int i = 0; i < 4; ++i) {
                acc[i][0] = fmaf(a[i], w0, acc[i][0]);
                acc[i][1] = fmaf(a[i], w1, acc[i][1]);
            }
        }
        #pragma unroll
        for (int j = 0; j < 2; ++j) {
            int c = cb * 2 + j;
            float bb = b1[c], s = s1v[c], t = t1v[c];
            float v[4];
            #pragma unroll
            for (int i = 0; i < 4; ++i)
                v[i] = fmaxf(fmaf(acc[i][j] + bb, s, t), 0.f);
            *reinterpret_cast<float4*>(&x1s[c * 36 + pb * 4]) =
                *reinterpret_cast<float4*>(v);
        }
    }
    __syncthreads();

    { // L2: 64 -> 128  (4 channels/thread)
        float acc[4][4] = {};
        #pragma unroll 4
        for (int k = 0; k < 64; ++k) {
            float a[4], w[4];
            *reinterpret_cast<float4*>(a) =
                *reinterpret_cast<const float4*>(&x1s[k * 36 + pb * 4]);
            *reinterpret_cast<float4*>(w) =
                *reinterpret_cast<const float4*>(&W2[k * 128 + cb * 4]);
            #pragma unroll
            for (int i = 0; i < 4; ++i)
                #pragma unroll
                for (int j = 0; j < 4; ++j)
                    acc[i][j] = fmaf(a[i], w[j], acc[i][j]);
        }
        #pragma unroll
        for (int j = 0; j < 4; ++j) {
            int c = cb * 4 + j;
            float bb = b2[c], s = s2v[c], t = t2v[c];
            float v[4];
            #pragma unroll
            for (int i = 0; i < 4; ++i)
                v[i] = fmaxf(fmaf(acc[i][j] + bb, s, t), 0.f);
            *reinterpret_cast<float4*>(&x2s[c * 36 + pb * 4]) =
                *reinterpret_cast<float4*>(v);
        }
    }
    __syncthreads();

    { // L3: 128 -> 256  (8 channels/thread), epilogue -> x3A bf16 fragments
        float acc[4][8] = {};
        #pragma unroll 4
        for (int k = 0; k < 128; ++k) {
            float a[4];
            *reinterpret_cast<float4*>(a) =
                *reinterpret_cast<const float4*>(&x2s[k * 36 + pb * 4]);
            #pragma unroll
            for (int h = 0; h < 2; ++h) {
                float w[4];
                *reinterpret_cast<float4*>(w) =
                    *reinterpret_cast<const float4*>(&W3[k * 256 + cb * 8 + h * 4]);
                #pragma unroll
                for (int i = 0; i < 4; ++i)
                    #pragma unroll
                    for (int j = 0; j < 4; ++j)
                        acc[i][h * 4 + j] = fmaf(a[i], w[j], acc[i][h * 4 + j]);
            }
        }
        // epilogue: BN+ReLU, write A-fragment-linear bf16
        // thread owns m = pb*4+i, c = cb*8+jj  ->  kc = cb>>2 (fixed),
        // lane = (m&15) + (cb&3)*16, j-index = jj (contiguous 8 = one b128)
        int kc = cb >> 2, lhi = (cb & 3) * 16;
        #pragma unroll
        for (int i = 0; i < 4; ++i) {
            int m = pb * 4 + i;
            int mt = m >> 4;
            int lane = (m & 15) + lhi;
            unsigned short o[8];
            #pragma unroll
            for (int jj = 0; jj < 8; ++jj) {
                int c = cb * 8 + jj;
                float v = fmaxf(fmaf(acc[i][jj] + b3[c], s3v[c], t3v[c]), 0.f);
                o[jj] = f2bf(v);
            }
            *reinterpret_cast<uint4*>(x3A + ((mt * 8 + kc) * 64 + lane) * 8) =
                *reinterpret_cast<const uint4*>(o);
        }
    }
    // NOTE: no sync here; first sync inside L4 loop covers x3A visibility.

    { // L4: 256 -> 512 via MFMA. 4 waves x (M32 x N64) per N-half.
        int w = tid >> 6, lane = tid & 63;
        const uint4* w4cv = reinterpret_cast<const uint4*>(w4c);
        #pragma unroll 1
        for (int nh = 0; nh < 2; ++nh) {
            floatx4 acc[2][4];
            #pragma unroll
            for (int mt = 0; mt < 2; ++mt)
                #pragma unroll
                for (int t = 0; t < 4; ++t)
                    acc[mt][t] = (floatx4)0.f;

            uint4 pf[4];
            {
                const uint4* g = reinterpret_cast<const uint4*>(W4f) +
                                 (size_t)(nh * 8 + 0) * 1024;
                #pragma unroll
                for (int r = 0; r < 4; ++r) pf[r] = g[tid * 4 + r];
            }
            #pragma unroll 1
            for (int kc = 0; kc < 8; ++kc) {
                __syncthreads();                       // prev chunk consumed / x3A ready
                #pragma unroll
                for (int r = 0; r < 4; ++r)
                    const_cast<uint4*>(w4cv)[tid * 4 + r] = pf[r];
                if (kc < 7) {
                    const uint4* g = reinterpret_cast<const uint4*>(W4f) +
                                     (size_t)(nh * 8 + kc + 1) * 1024;
                    #pragma unroll
                    for (int r = 0; r < 4; ++r) pf[r] = g[tid * 4 + r];
                }
                __syncthreads();                       // chunk visible
                short8 a0 = *reinterpret_cast<const short8*>(
                    x3A + ((0 * 8 + kc) * 64 + lane) * 8);
                short8 a1 = *reinterpret_cast<const short8*>(
                    x3A + ((1 * 8 + kc) * 64 + lane) * 8);
                #pragma unroll
                for (int t = 0; t < 4; ++t) {
                    short8 bf = *reinterpret_cast<const short8*>(
                        w4c + ((w * 4 + t) * 64 + lane) * 8);
                    acc[0][t] = __builtin_amdgcn_mfma_f32_16x16x32_bf16(
                        a0, bf, acc[0][t], 0, 0, 0);
                    acc[1][t] = __builtin_amdgcn_mfma_f32_16x16x32_bf16(
                        a1, bf, acc[1][t], 0, 0, 0);
                }
            }
            __syncthreads();                           // all reads of w4c done
            // epilogue: acc (+b4) -> rep[m][256] bf16 (rep = w4c area)
            unsigned short* rep = w4c;
            #pragma unroll
            for (int mt = 0; mt < 2; ++mt)
                #pragma unroll
                for (int t = 0; t < 4; ++t) {
                    int cl = w * 64 + t * 16 + (lane & 15);
                    float bb = b4[nh * 256 + cl];
                    #pragma unroll
                    for (int r = 0; r < 4; ++r) {
                        int m = mt * 16 + (lane >> 4) * 4 + r;
                        rep[m * 256 + cl] = f2bf(acc[mt][t][r] + bb);
                    }
                }
            __syncthreads();                           // rep complete
            // coalesced copy-out: 16KB -> x4 rows
            #pragma unroll
            for (int r = 0; r < 4; ++r) {
                int q = tid * 4 + r;                   // uint4 index (1024 total)
                int m = q >> 5, co = (q & 31) * 8;
                *reinterpret_cast<uint4*>(
                    &x4out[((size_t)(b * N_ + n0 + m)) * 512 + nh * 256 + co]) =
                    reinterpret_cast<const uint4*>(rep)[q];
            }
        }
    }
}

// ---------------- per-voxel max-pool + compression ----------------
__global__ __launch_bounds__(256) void k_pool(
        const int* __restrict__ head, const int* __restrict__ nxt,
        const unsigned short* __restrict__ x4,
        const float* __restrict__ Wc, const float* __restrict__ bcv,
        float* __restrict__ out)
{
    __shared__ float mxsh[8][512];
    __shared__ float partsh[64][32];
    __shared__ float compsh[8][33];
    __shared__ int   gh[8];
    int tid = threadIdx.x;

    #pragma unroll 1
    for (int it = 0; it < 20; ++it) {
        int gbase = (it * 2160 + blockIdx.x) * 8;   // 2160*8*20 = 345600 = B*HW
        {   // phase 1: chain walk + segment max (32 lanes x 16 channels each)
            int g = tid >> 5, l = tid & 31;
            int gid = gbase + g;
            int h = head[gid];
            if (l == 0) gh[g] = h;
            if (h >= 0) {
                float mx[16];
                #pragma unroll
                for (int j = 0; j < 16; ++j) mx[j] = -3.0e38f;
                int cur = h;
                while (cur >= 0) {
                    const unsigned short* row = x4 + (size_t)cur * 512 + l * 16;
                    uint4 r0 = *reinterpret_cast<const uint4*>(row);
                    uint4 r1 = *reinterpret_cast<const uint4*>(row + 8);
                    unsigned rr[8] = {r0.x, r0.y, r0.z, r0.w, r1.x, r1.y, r1.z, r1.w};
                    #pragma unroll
                    for (int q = 0; q < 8; ++q) {
                        mx[2*q]   = fmaxf(mx[2*q],   __uint_as_float((rr[q] & 0xFFFFu) << 16));
                        mx[2*q+1] = fmaxf(mx[2*q+1], __uint_as_float(rr[q] & 0xFFFF0000u));
                    }
                    cur = nxt[cur];
                }
                #pragma unroll
                for (int j = 0; j < 16; ++j) mxsh[g][l * 16 + j] = mx[j];
            } else {
                #pragma unroll
                for (int j = 0; j < 16; ++j) mxsh[g][l * 16 + j] = 0.f;
            }
        }
        __syncthreads();
        {   // phase 2a: partial dots, Wc value reused across all 8 voxels
            int j = tid & 31, s = tid >> 5;          // c-slice [s*64, s*64+64)
            float part[8] = {0.f,0.f,0.f,0.f,0.f,0.f,0.f,0.f};
            const float* wc = Wc + j;
            #pragma unroll 4
            for (int c = s * 64; c < s * 64 + 64; ++c) {
                float w = wc[c * 32];
                #pragma unroll
                for (int g = 0; g < 8; ++g)
                    part[g] = fmaf(mxsh[g][c], w, part[g]);
            }
            #pragma unroll
            for (int g = 0; g < 8; ++g) partsh[s * 8 + g][j] = part[g];
        }
        __syncthreads();
        {   // phase 2b: reduce 8 slices + bias + relu
            int j = tid & 31, g = tid >> 5;
            float s = bcv[j];
            #pragma unroll
            for (int s2 = 0; s2 < 8; ++s2) s += partsh[s2 * 8 + g][j];
            compsh[g][j] = fmaxf(s, 0.f);
        }
        __syncthreads();
        {   // phase 3: transposed scatter (float32 output), 8 voxels x 32 ch
            int gi = tid & 7, j = tid >> 3;
            if (gh[gi] >= 0) {
                int gid = gbase + gi;
                int b = gid / HWv, v = gid - b * HWv;
                int x = v / GYv, y = v - x * GYv;
                out[(((size_t)b * NHv + j) * GXv + x) * GYv + y] = compsh[gi][j];
            }
        }
        __syncthreads();
    }
}

extern "C" void kernel_launch(void* const* d_in, const int* in_sizes, int n_in,
                              void* d_out, int out_size, void* d_ws, size_t ws_size,
                              hipStream_t stream) {
    const float* pt_fea = (const float*)d_in[0];
    const int*   xy     = (const int*)d_in[1];
    const float* s0v = (const float*)d_in[2];  const float* t0v = (const float*)d_in[3];
    const float* s1v = (const float*)d_in[4];  const float* t1v = (const float*)d_in[5];
    const float* s2v = (const float*)d_in[6];  const float* t2v = (const float*)d_in[7];
    const float* s3v = (const float*)d_in[8];  const float* t3v = (const float*)d_in[9];
    const float* W1  = (const float*)d_in[10]; const float* b1  = (const float*)d_in[11];
    const float* W2  = (const float*)d_in[12]; const float* b2  = (const float*)d_in[13];
    const float* W3  = (const float*)d_in[14]; const float* b3  = (const float*)d_in[15];
    const float* W4  = (const float*)d_in[16]; const float* b4  = (const float*)d_in[17];
    const float* Wc  = (const float*)d_in[18]; const float* bc  = (const float*)d_in[19];

    // workspace: x4 bf16 (134.2MB) | head (1.38MB) | nxt (0.52MB) | W4ws (0.26MB)
    char* ws = (char*)d_ws;
    unsigned short* x4   = (unsigned short*)ws;
    int* head            = (int*)(ws + (size_t)B_ * N_ * 512 * 2);
    int* nxt             = (int*)(ws + (size_t)B_ * N_ * 512 * 2 + (size_t)B_ * HWv * 4);
    unsigned short* W4ws = (unsigned short*)(ws + (size_t)B_ * N_ * 512 * 2 +
                                             (size_t)B_ * HWv * 4 + (size_t)B_ * N_ * 4);

    hipLaunchKernelGGL(k_init_head, dim3(1350),  dim3(256), 0, stream, head);
    hipLaunchKernelGGL(k_zero_out,  dim3(10800), dim3(256), 0, stream, (uint4*)d_out);
    hipLaunchKernelGGL(k_chain,     dim3(512),   dim3(256), 0, stream, xy, head, nxt);
    hipLaunchKernelGGL(k_cvtW4,     dim3(64),    dim3(256), 0, stream, W4, W4ws);
    hipLaunchKernelGGL(k_mlp,       dim3(4096),  dim3(256), 0, stream,
        pt_fea, s0v, t0v, s1v, t1v, s2v, t2v, s3v, t3v,
        W1, b1, W2, b2, W3, b3, W4ws, b4, x4);
    hipLaunchKernelGGL(k_pool,      dim3(2160),  dim3(256), 0, stream,
        head, nxt, x4, Wc, bc, (float*)d_out);
}

// Round 6
// 241.373 us; speedup vs baseline: 4.5607x; 3.0464x over previous
//
#include <hip/hip_runtime.h>
#include <cstdint>
#include <cstddef>

#define B_   2
#define N_   65536
#define GXv  480
#define GYv  360
#define NHv  32
#define HWv  (GXv*GYv)          // 172800

typedef __attribute__((ext_vector_type(8))) short short8;
typedef __attribute__((ext_vector_type(4))) float floatx4;

// round-to-nearest-even f32 -> bf16
__device__ __forceinline__ unsigned short f2bf(float f) {
    unsigned u = __float_as_uint(f);
    u += 0x7FFFu + ((u >> 16) & 1u);
    return (unsigned short)(u >> 16);
}

// async global->LDS, 16B per lane (dest linear base + tid*16, lane-contiguous)
__device__ __forceinline__ void issue16(const void* g, void* l) {
    __builtin_amdgcn_global_load_lds(
        (const __attribute__((address_space(1))) unsigned int*)g,
        (__attribute__((address_space(3))) unsigned int*)l, 16, 0, 0);
}
__device__ __forceinline__ void issue_chunk16k(const void* g, void* l, int tid) {
    #pragma unroll
    for (int i = 0; i < 4; ++i)
        issue16((const char*)g + tid * 16 + i * 4096,
                (char*)l + tid * 16 + i * 4096);
}

// ---------------- init / zero ----------------
__global__ void k_init_head(int* head, int* cnt) {
    int i = blockIdx.x * 256 + threadIdx.x;
    if (i < B_ * HWv) head[i] = -1;
    if (i == 0) cnt[0] = 0;
}
__global__ void k_zero_out(uint4* out) {
    int i = blockIdx.x * 256 + threadIdx.x;
    if (i < (B_ * NHv * HWv * 4) / 16) out[i] = make_uint4(0, 0, 0, 0);
}

// ---------------- voxel bucketing + occupied-voxel compaction ----------------
// Chain/list order is atomic-nondeterministic, but max-pool is commutative and
// each voxel writes only its own output location -> output deterministic.
// (keep-cap MAX_PT=256 never triggers: 65536 pts over 129600 voxels.)
__global__ void k_chain(const int* __restrict__ xy, int* head, int* nxt,
                        int* list, int* cnt) {
    int i = blockIdx.x * 256 + threadIdx.x;
    if (i >= B_ * N_) return;
    int b = i >> 16;
    int x = xy[2 * i], y = xy[2 * i + 1];
    int hidx = b * HWv + x * GYv + y;
    int prev = atomicExch(&head[hidx], i);
    nxt[i] = prev;
    if (prev == -1) { int s = atomicAdd(cnt, 1); list[s] = hidx; }
}

// ---------------- weight -> bf16 B-fragment-linear ----------------
// dst[((kc*NT + nt)*64 + l)*8 + j] = bf16(W[(kc*32 + (l>>4)*8 + j)*N + nt*16 + (l&15)])
__global__ void k_cvtB(const float* __restrict__ W, unsigned short* __restrict__ dst,
                       int K, int N) {
    int d = blockIdx.x * 256 + threadIdx.x;
    if (d >= (K * N) / 8) return;
    int l = d & 63;
    int g = d >> 6;
    int NT = N >> 4;
    int kc = g / NT, nt = g - kc * NT;
    int k0 = kc * 32 + (l >> 4) * 8, n = nt * 16 + (l & 15);
    __align__(16) unsigned short o[8];
    #pragma unroll
    for (int j = 0; j < 8; ++j) o[j] = f2bf(W[(size_t)(k0 + j) * N + n]);
    *reinterpret_cast<uint4*>(dst + (size_t)d * 8) = *reinterpret_cast<const uint4*>(o);
}

// 16 MFMAs: one chunk (K=32, wave's 4 n-tiles), acc[4 mt][4 nt]
template<int KC>
__device__ __forceinline__ void mfma16(const unsigned short* xA, int kc,
        const unsigned short* cc, int w, int lane, floatx4 (&acc)[4][4]) {
    short8 a[4];
    #pragma unroll
    for (int mt = 0; mt < 4; ++mt)
        a[mt] = *reinterpret_cast<const short8*>(xA + ((mt * KC + kc) * 64 + lane) * 8);
    #pragma unroll
    for (int nt = 0; nt < 4; ++nt) {
        short8 bf = *reinterpret_cast<const short8*>(cc + ((w * 4 + nt) * 64 + lane) * 8);
        #pragma unroll
        for (int mt = 0; mt < 4; ++mt)
            acc[mt][nt] = __builtin_amdgcn_mfma_f32_16x16x32_bf16(a[mt], bf, acc[mt][nt], 0, 0, 0);
    }
}

// ---------------- fused point MLP, all-MFMA ----------------
// 64-pt tiles, 4 waves. LDS 64KB:
//  [0,8K)=x1A  [8K,24K)=x2A  [0,32K)=x3A(after L3)  [8K,~10K)=x0 staging
//  [32K,48K)=cb0  [48K,64K)=cb1  (weight chunk ring; [32K,64K)=rep in L4 epi)
__global__ __launch_bounds__(256) void k_mlp(
        const float* __restrict__ pt_fea,
        const float* __restrict__ s0v, const float* __restrict__ t0v,
        const float* __restrict__ s1v, const float* __restrict__ t1v,
        const float* __restrict__ s2v, const float* __restrict__ t2v,
        const float* __restrict__ s3v, const float* __restrict__ t3v,
        const float* __restrict__ W1, const float* __restrict__ b1,
        const unsigned short* __restrict__ W2B, const float* __restrict__ b2,
        const unsigned short* __restrict__ W3B, const float* __restrict__ b3,
        const unsigned short* __restrict__ W4B, const float* __restrict__ b4,
        unsigned short* __restrict__ x4out)
{
    __shared__ __align__(16) char smem[65536];
    unsigned short* x1A = (unsigned short*)smem;
    unsigned short* x2A = (unsigned short*)(smem + 8192);
    unsigned short* x3A = (unsigned short*)smem;
    float*          x0s = (float*)(smem + 8192);
    unsigned short* cb0 = (unsigned short*)(smem + 32768);
    unsigned short* cb1 = (unsigned short*)(smem + 49152);
    unsigned short* rep = (unsigned short*)(smem + 32768);

    int tid = threadIdx.x;
    int w = tid >> 6, lane = tid & 63;
    int bid = blockIdx.x;                    // 2048 blocks
    int b = bid >> 10, n0 = (bid & 1023) << 6;
    const float* fea = pt_fea + ((size_t)(b * N_ + n0)) * 9;

    issue_chunk16k(W2B, cb0, tid);           // W2 whole (16KB)
    for (int idx = tid; idx < 576; idx += 256) {
        int kk = idx % 9;
        x0s[idx] = fea[idx] * s0v[kk] + t0v[kk];
    }
    __syncthreads();                         // x0 + W2B ready

    // ---- L1: 9->64 vector f32, writes x1A (A-frag bf16, KC=2) ----
    {
        int p = tid & 63, q = tid >> 6;
        float a0[9];
        #pragma unroll
        for (int k = 0; k < 9; ++k) a0[k] = x0s[p * 9 + k];
        float acc1[16];
        #pragma unroll
        for (int c = 0; c < 16; ++c) acc1[c] = 0.f;
        #pragma unroll
        for (int k = 0; k < 9; ++k) {
            #pragma unroll
            for (int c4 = 0; c4 < 4; ++c4) {
                float4 wv = *reinterpret_cast<const float4*>(&W1[k * 64 + q * 16 + c4 * 4]);
                acc1[c4*4+0] = fmaf(a0[k], wv.x, acc1[c4*4+0]);
                acc1[c4*4+1] = fmaf(a0[k], wv.y, acc1[c4*4+1]);
                acc1[c4*4+2] = fmaf(a0[k], wv.z, acc1[c4*4+2]);
                acc1[c4*4+3] = fmaf(a0[k], wv.w, acc1[c4*4+3]);
            }
        }
        #pragma unroll
        for (int h = 0; h < 2; ++h) {
            __align__(16) unsigned short o[8];
            #pragma unroll
            for (int j = 0; j < 8; ++j) {
                int c = q * 16 + h * 8 + j;
                o[j] = f2bf(fmaxf(fmaf(acc1[h * 8 + j] + b1[c], s1v[c], t1v[c]), 0.f));
            }
            int lane2 = (p & 15) + (((q & 1) * 2 + h) << 4);
            *reinterpret_cast<uint4*>(x1A + (((p >> 4) * 2 + (q >> 1)) * 64 + lane2) * 8) =
                *reinterpret_cast<const uint4*>(o);
        }
    }
    issue_chunk16k((const char*)W3B, cb1, tid);      // W3 c0
    __syncthreads();                                 // x1A visible, W3c0 in

    // ---- L2: 64->128 MFMA (W2B whole in cb0) ----
    {
        floatx4 acc[4][2];
        #pragma unroll
        for (int mt = 0; mt < 4; ++mt)
            #pragma unroll
            for (int nt = 0; nt < 2; ++nt) acc[mt][nt] = (floatx4)0.f;
        #pragma unroll
        for (int kc = 0; kc < 2; ++kc) {
            short8 a[4];
            #pragma unroll
            for (int mt = 0; mt < 4; ++mt)
                a[mt] = *reinterpret_cast<const short8*>(x1A + ((mt * 2 + kc) * 64 + lane) * 8);
            #pragma unroll
            for (int nt = 0; nt < 2; ++nt) {
                short8 bf = *reinterpret_cast<const short8*>(
                    cb0 + ((kc * 8 + w * 2 + nt) * 64 + lane) * 8);
                #pragma unroll
                for (int mt = 0; mt < 4; ++mt)
                    acc[mt][nt] = __builtin_amdgcn_mfma_f32_16x16x32_bf16(a[mt], bf, acc[mt][nt], 0, 0, 0);
            }
        }
        __syncthreads();                             // cb0 free
        issue_chunk16k((const char*)W3B + 16384, cb0, tid);  // W3 c1
        #pragma unroll
        for (int nt = 0; nt < 2; ++nt) {
            int c = (w * 2 + nt) * 16 + (lane & 15);
            float bb = b2[c], sc = s2v[c], tt = t2v[c];
            #pragma unroll
            for (int mt = 0; mt < 4; ++mt)
                #pragma unroll
                for (int r = 0; r < 4; ++r) {
                    int ml = (lane >> 4) * 4 + r;
                    float v = fmaxf(fmaf(acc[mt][nt][r] + bb, sc, tt), 0.f);
                    x2A[((mt * 4 + (c >> 5)) * 64 + ml + (((c >> 3) & 3) << 4)) * 8 + (c & 7)] = f2bf(v);
                }
        }
    }
    __syncthreads();                                 // x2A visible, W3c1 in

    // ---- L3: 128->256 MFMA, 4 chunks (c0:cb1 c1:cb0 c2:cb1 c3:cb0) ----
    {
        floatx4 acc3[4][4];
        #pragma unroll
        for (int mt = 0; mt < 4; ++mt)
            #pragma unroll
            for (int nt = 0; nt < 4; ++nt) acc3[mt][nt] = (floatx4)0.f;
        #pragma unroll
        for (int kc = 0; kc < 4; ++kc) {
            mfma16<4>(x2A, kc, (kc & 1) ? cb0 : cb1, w, lane, acc3);
            __syncthreads();
            if (kc == 0)      issue_chunk16k((const char*)W3B + 2 * 16384, cb1, tid);
            else if (kc == 1) issue_chunk16k((const char*)W3B + 3 * 16384, cb0, tid);
            else if (kc == 2) issue_chunk16k((const char*)W4B, cb1, tid);        // W4 kc0 nh0
            else              issue_chunk16k((const char*)W4B + 32768, cb0, tid); // W4 kc1 nh0
        }
        // epilogue -> x3A (overwrites x1A/x2A; all reads done at last barrier)
        #pragma unroll
        for (int nt = 0; nt < 4; ++nt) {
            int c = w * 64 + nt * 16 + (lane & 15);
            float bb = b3[c], sc = s3v[c], tt = t3v[c];
            #pragma unroll
            for (int mt = 0; mt < 4; ++mt)
                #pragma unroll
                for (int r = 0; r < 4; ++r) {
                    int ml = (lane >> 4) * 4 + r;
                    float v = fmaxf(fmaf(acc3[mt][nt][r] + bb, sc, tt), 0.f);
                    x3A[((mt * 8 + (c >> 5)) * 64 + ml + (((c >> 3) & 3) << 4)) * 8 + (c & 7)] = f2bf(v);
                }
        }
    }
    __syncthreads();                                 // x3A visible, W4 kc0/kc1 in

    // ---- L4: 256->512 MFMA, 2 halves x 8 chunks ----
    #pragma unroll 1
    for (int nh = 0; nh < 2; ++nh) {
        floatx4 acc4[4][4];
        #pragma unroll
        for (int mt = 0; mt < 4; ++mt)
            #pragma unroll
            for (int nt = 0; nt < 4; ++nt) acc4[mt][nt] = (floatx4)0.f;
        #pragma unroll
        for (int kc = 0; kc < 8; ++kc) {
            mfma16<8>(x3A, kc, (kc & 1) ? cb0 : cb1, w, lane, acc4);
            __syncthreads();
            if (kc < 6)
                issue_chunk16k((const char*)W4B + (size_t)(kc + 2) * 32768 + nh * 16384,
                               (kc & 1) ? cb0 : cb1, tid);
        }
        // epilogue: acc + b4 -> rep[64][256] bf16
        #pragma unroll
        for (int nt = 0; nt < 4; ++nt) {
            int cl = w * 64 + nt * 16 + (lane & 15);
            float bb = b4[nh * 256 + cl];
            #pragma unroll
            for (int mt = 0; mt < 4; ++mt)
                #pragma unroll
                for (int r = 0; r < 4; ++r) {
                    int m = mt * 16 + (lane >> 4) * 4 + r;
                    rep[m * 256 + cl] = f2bf(acc4[mt][nt][r] + bb);
                }
        }
        __syncthreads();                             // rep visible
        // copy-out: rep is [64 rows][256 cols] bf16 = 32 uint4 per row
        #pragma unroll
        for (int r = 0; r < 8; ++r) {
            int q = r * 256 + tid;                   // uint4 index, 0..2047
            int m = q >> 5, co = (q & 31) * 8;       // FIXED (was >>4 / &15)
            *reinterpret_cast<uint4*>(
                &x4out[((size_t)(b * N_ + n0 + m)) * 512 + nh * 256 + co]) =
                reinterpret_cast<const uint4*>(rep)[q];
        }
        if (nh == 0) {
            __syncthreads();                         // rep reads done, ring free
            issue_chunk16k((const char*)W4B + 16384, cb1, tid);          // kc0 nh1
            issue_chunk16k((const char*)W4B + 32768 + 16384, cb0, tid);  // kc1 nh1
            __syncthreads();                         // drained
        }
    }
}

// ---------------- per-voxel max-pool + compression (occupied only) ----------------
__global__ __launch_bounds__(256) void k_pool(
        const int* __restrict__ head, const int* __restrict__ nxt,
        const unsigned short* __restrict__ x4,
        const float* __restrict__ Wc, const float* __restrict__ bcv,
        float* __restrict__ out, const int* __restrict__ list,
        const int* __restrict__ cnt)
{
    __shared__ float mxsh[8][512];
    __shared__ float partsh[64][32];
    __shared__ float compsh[8][33];
    int tid = threadIdx.x;
    int nocc = cnt[0];

    for (int base = blockIdx.x * 8; base < nocc; base += 2048 * 8) {
        {   // phase 1: chain walk + segment max (32 lanes x 16 ch)
            int g = tid >> 5, l = tid & 31;
            int idx = base + g;
            if (idx < nocc) {
                int gid = list[idx];
                float mx[16];
                #pragma unroll
                for (int j = 0; j < 16; ++j) mx[j] = -3.0e38f;
                int cur = head[gid];
                while (cur >= 0) {
                    const unsigned short* row = x4 + (size_t)cur * 512 + l * 16;
                    uint4 r0 = *reinterpret_cast<const uint4*>(row);
                    uint4 r1 = *reinterpret_cast<const uint4*>(row + 8);
                    unsigned rr[8] = {r0.x, r0.y, r0.z, r0.w, r1.x, r1.y, r1.z, r1.w};
                    #pragma unroll
                    for (int q = 0; q < 8; ++q) {
                        mx[2*q]   = fmaxf(mx[2*q],   __uint_as_float((rr[q] & 0xFFFFu) << 16));
                        mx[2*q+1] = fmaxf(mx[2*q+1], __uint_as_float(rr[q] & 0xFFFF0000u));
                    }
                    cur = nxt[cur];
                }
                #pragma unroll
                for (int j = 0; j < 16; ++j) mxsh[g][l * 16 + j] = mx[j];
            } else {
                #pragma unroll
                for (int j = 0; j < 16; ++j) mxsh[g][l * 16 + j] = 0.f;
            }
        }
        __syncthreads();
        {   // phase 2a: partial dots, each Wc value reused across 8 voxels
            int j = tid & 31, s = tid >> 5;
            float part[8] = {0.f,0.f,0.f,0.f,0.f,0.f,0.f,0.f};
            const float* wc = Wc + j;
            #pragma unroll 4
            for (int c = s * 64; c < s * 64 + 64; ++c) {
                float w = wc[c * 32];
                #pragma unroll
                for (int g = 0; g < 8; ++g)
                    part[g] = fmaf(mxsh[g][c], w, part[g]);
            }
            #pragma unroll
            for (int g = 0; g < 8; ++g) partsh[s * 8 + g][j] = part[g];
        }
        __syncthreads();
        {   // phase 2b: reduce + bias + relu
            int j = tid & 31, g = tid >> 5;
            float s = bcv[j];
            #pragma unroll
            for (int s2 = 0; s2 < 8; ++s2) s += partsh[s2 * 8 + g][j];
            compsh[g][j] = fmaxf(s, 0.f);
        }
        __syncthreads();
        {   // phase 3: transposed scatter (f32 out)
            int gi = tid & 7, j = tid >> 3;
            int idx = base + gi;
            if (idx < nocc) {
                int gid = list[idx];
                int b = gid / HWv, v = gid - b * HWv;
                int x = v / GYv, y = v - x * GYv;
                out[(((size_t)b * NHv + j) * GXv + x) * GYv + y] = compsh[gi][j];
            }
        }
        __syncthreads();
    }
}

extern "C" void kernel_launch(void* const* d_in, const int* in_sizes, int n_in,
                              void* d_out, int out_size, void* d_ws, size_t ws_size,
                              hipStream_t stream) {
    const float* pt_fea = (const float*)d_in[0];
    const int*   xy     = (const int*)d_in[1];
    const float* s0v = (const float*)d_in[2];  const float* t0v = (const float*)d_in[3];
    const float* s1v = (const float*)d_in[4];  const float* t1v = (const float*)d_in[5];
    const float* s2v = (const float*)d_in[6];  const float* t2v = (const float*)d_in[7];
    const float* s3v = (const float*)d_in[8];  const float* t3v = (const float*)d_in[9];
    const float* W1  = (const float*)d_in[10]; const float* b1  = (const float*)d_in[11];
    const float* W2  = (const float*)d_in[12]; const float* b2  = (const float*)d_in[13];
    const float* W3  = (const float*)d_in[14]; const float* b3  = (const float*)d_in[15];
    const float* W4  = (const float*)d_in[16]; const float* b4  = (const float*)d_in[17];
    const float* Wc  = (const float*)d_in[18]; const float* bc  = (const float*)d_in[19];

    // workspace: x4 | head | nxt | list | cnt | W2B | W3B | W4B
    char* ws = (char*)d_ws;
    size_t off = 0;
    unsigned short* x4   = (unsigned short*)(ws + off); off += (size_t)B_ * N_ * 512 * 2;
    int* head            = (int*)(ws + off);            off += (size_t)B_ * HWv * 4;
    int* nxt             = (int*)(ws + off);            off += (size_t)B_ * N_ * 4;
    int* list            = (int*)(ws + off);            off += (size_t)B_ * N_ * 4;
    int* cnt             = (int*)(ws + off);            off += 256;
    unsigned short* W2B  = (unsigned short*)(ws + off); off += 64 * 128 * 2;
    unsigned short* W3B  = (unsigned short*)(ws + off); off += 128 * 256 * 2;
    unsigned short* W4B  = (unsigned short*)(ws + off); off += 256 * 512 * 2;

    hipLaunchKernelGGL(k_init_head, dim3(1350),  dim3(256), 0, stream, head, cnt);
    hipLaunchKernelGGL(k_zero_out,  dim3(10800), dim3(256), 0, stream, (uint4*)d_out);
    hipLaunchKernelGGL(k_chain,     dim3(512),   dim3(256), 0, stream, xy, head, nxt, list, cnt);
    hipLaunchKernelGGL(k_cvtB,      dim3(4),     dim3(256), 0, stream, W2, W2B, 64, 128);
    hipLaunchKernelGGL(k_cvtB,      dim3(16),    dim3(256), 0, stream, W3, W3B, 128, 256);
    hipLaunchKernelGGL(k_cvtB,      dim3(64),    dim3(256), 0, stream, W4, W4B, 256, 512);
    hipLaunchKernelGGL(k_mlp,       dim3(2048),  dim3(256), 0, stream,
        pt_fea, s0v, t0v, s1v, t1v, s2v, t2v, s3v, t3v,
        W1, b1, W2B, b2, W3B, b3, W4B, b4, x4);
    hipLaunchKernelGGL(k_pool,      dim3(2048),  dim3(256), 0, stream,
        head, nxt, x4, Wc, bc, (float*)d_out, list, cnt);
}

// Round 7
// 196.715 us; speedup vs baseline: 5.5961x; 1.2270x over previous
//
#include <hip/hip_runtime.h>
#include <cstdint>
#include <cstddef>

#define B_   2
#define N_   65536
#define GXv  480
#define GYv  360
#define NHv  32
#define HWv  (GXv*GYv)          // 172800

typedef __attribute__((ext_vector_type(8))) short short8;
typedef __attribute__((ext_vector_type(4))) float floatx4;

// round-to-nearest-even f32 -> bf16
__device__ __forceinline__ unsigned short f2bf(float f) {
    unsigned u = __float_as_uint(f);
    u += 0x7FFFu + ((u >> 16) & 1u);
    return (unsigned short)(u >> 16);
}

// async global->LDS, 16B per lane (dest linear base + tid*16, lane-contiguous)
__device__ __forceinline__ void issue16(const void* g, void* l) {
    __builtin_amdgcn_global_load_lds(
        (const __attribute__((address_space(1))) unsigned int*)g,
        (__attribute__((address_space(3))) unsigned int*)l, 16, 0, 0);
}
__device__ __forceinline__ void issue_chunk16k(const void* g, void* l, int tid) {
    #pragma unroll
    for (int i = 0; i < 4; ++i)
        issue16((const char*)g + tid * 16 + i * 4096,
                (char*)l + tid * 16 + i * 4096);
}

// ---------------- init / zero ----------------
__global__ void k_init_head(int* head, int* cnt) {
    int i = blockIdx.x * 256 + threadIdx.x;
    if (i < B_ * HWv) head[i] = -1;
    if (i == 0) cnt[0] = 0;
}
__global__ void k_zero_out(uint4* out) {
    int i = blockIdx.x * 256 + threadIdx.x;
    if (i < (B_ * NHv * HWv * 4) / 16) out[i] = make_uint4(0, 0, 0, 0);
}

// ---------------- voxel bucketing + occupied-voxel compaction ----------------
// Chain/list order is atomic-nondeterministic, but max-pool is commutative and
// each voxel writes only its own output location -> output deterministic.
// (keep-cap MAX_PT=256 never triggers: 65536 pts over 129600 voxels.)
__global__ void k_chain(const int* __restrict__ xy, int* head, int* nxt,
                        int* list, int* cnt) {
    int i = blockIdx.x * 256 + threadIdx.x;
    if (i >= B_ * N_) return;
    int b = i >> 16;
    int x = xy[2 * i], y = xy[2 * i + 1];
    int hidx = b * HWv + x * GYv + y;
    int prev = atomicExch(&head[hidx], i);
    nxt[i] = prev;
    if (prev == -1) { int s = atomicAdd(cnt, 1); list[s] = hidx; }
}

// ---------------- weight -> bf16 B-fragment-linear ----------------
// dst[((kc*NT + nt)*64 + l)*8 + j] = bf16(W[(kc*32 + (l>>4)*8 + j)*N + nt*16 + (l&15)])
__global__ void k_cvtB(const float* __restrict__ W, unsigned short* __restrict__ dst,
                       int K, int N) {
    int d = blockIdx.x * 256 + threadIdx.x;
    if (d >= (K * N) / 8) return;
    int l = d & 63;
    int g = d >> 6;
    int NT = N >> 4;
    int kc = g / NT, nt = g - kc * NT;
    int k0 = kc * 32 + (l >> 4) * 8, n = nt * 16 + (l & 15);
    __align__(16) unsigned short o[8];
    #pragma unroll
    for (int j = 0; j < 8; ++j) o[j] = f2bf(W[(size_t)(k0 + j) * N + n]);
    *reinterpret_cast<uint4*>(dst + (size_t)d * 8) = *reinterpret_cast<const uint4*>(o);
}

// 16 MFMAs: one chunk (K=32, wave's 4 n-tiles), acc[4 mt][4 nt]
template<int KC>
__device__ __forceinline__ void mfma16(const unsigned short* xA, int kc,
        const unsigned short* cc, int w, int lane, floatx4 (&acc)[4][4]) {
    short8 a[4];
    #pragma unroll
    for (int mt = 0; mt < 4; ++mt)
        a[mt] = *reinterpret_cast<const short8*>(xA + ((mt * KC + kc) * 64 + lane) * 8);
    #pragma unroll
    for (int nt = 0; nt < 4; ++nt) {
        short8 bf = *reinterpret_cast<const short8*>(cc + ((w * 4 + nt) * 64 + lane) * 8);
        #pragma unroll
        for (int mt = 0; mt < 4; ++mt)
            acc[mt][nt] = __builtin_amdgcn_mfma_f32_16x16x32_bf16(a[mt], bf, acc[mt][nt], 0, 0, 0);
    }
}

// ---------------- fused point MLP, all-MFMA ----------------
__global__ __launch_bounds__(256) void k_mlp(
        const float* __restrict__ pt_fea,
        const float* __restrict__ s0v, const float* __restrict__ t0v,
        const float* __restrict__ s1v, const float* __restrict__ t1v,
        const float* __restrict__ s2v, const float* __restrict__ t2v,
        const float* __restrict__ s3v, const float* __restrict__ t3v,
        const float* __restrict__ W1, const float* __restrict__ b1,
        const unsigned short* __restrict__ W2B, const float* __restrict__ b2,
        const unsigned short* __restrict__ W3B, const float* __restrict__ b3,
        const unsigned short* __restrict__ W4B, const float* __restrict__ b4,
        unsigned short* __restrict__ x4out)
{
    __shared__ __align__(16) char smem[65536];
    unsigned short* x1A = (unsigned short*)smem;
    unsigned short* x2A = (unsigned short*)(smem + 8192);
    unsigned short* x3A = (unsigned short*)smem;
    float*          x0s = (float*)(smem + 8192);
    unsigned short* cb0 = (unsigned short*)(smem + 32768);
    unsigned short* cb1 = (unsigned short*)(smem + 49152);
    unsigned short* rep = (unsigned short*)(smem + 32768);

    int tid = threadIdx.x;
    int w = tid >> 6, lane = tid & 63;
    int bid = blockIdx.x;                    // 2048 blocks
    int b = bid >> 10, n0 = (bid & 1023) << 6;
    const float* fea = pt_fea + ((size_t)(b * N_ + n0)) * 9;

    issue_chunk16k(W2B, cb0, tid);           // W2 whole (16KB)
    for (int idx = tid; idx < 576; idx += 256) {
        int kk = idx % 9;
        x0s[idx] = fea[idx] * s0v[kk] + t0v[kk];
    }
    __syncthreads();                         // x0 + W2B ready

    // ---- L1: 9->64 vector f32, writes x1A (A-frag bf16, KC=2) ----
    {
        int p = tid & 63, q = tid >> 6;
        float a0[9];
        #pragma unroll
        for (int k = 0; k < 9; ++k) a0[k] = x0s[p * 9 + k];
        float acc1[16];
        #pragma unroll
        for (int c = 0; c < 16; ++c) acc1[c] = 0.f;
        #pragma unroll
        for (int k = 0; k < 9; ++k) {
            #pragma unroll
            for (int c4 = 0; c4 < 4; ++c4) {
                float4 wv = *reinterpret_cast<const float4*>(&W1[k * 64 + q * 16 + c4 * 4]);
                acc1[c4*4+0] = fmaf(a0[k], wv.x, acc1[c4*4+0]);
                acc1[c4*4+1] = fmaf(a0[k], wv.y, acc1[c4*4+1]);
                acc1[c4*4+2] = fmaf(a0[k], wv.z, acc1[c4*4+2]);
                acc1[c4*4+3] = fmaf(a0[k], wv.w, acc1[c4*4+3]);
            }
        }
        #pragma unroll
        for (int h = 0; h < 2; ++h) {
            __align__(16) unsigned short o[8];
            #pragma unroll
            for (int j = 0; j < 8; ++j) {
                int c = q * 16 + h * 8 + j;
                o[j] = f2bf(fmaxf(fmaf(acc1[h * 8 + j] + b1[c], s1v[c], t1v[c]), 0.f));
            }
            int lane2 = (p & 15) + (((q & 1) * 2 + h) << 4);
            *reinterpret_cast<uint4*>(x1A + (((p >> 4) * 2 + (q >> 1)) * 64 + lane2) * 8) =
                *reinterpret_cast<const uint4*>(o);
        }
    }
    issue_chunk16k((const char*)W3B, cb1, tid);      // W3 c0
    __syncthreads();                                 // x1A visible, W3c0 in

    // ---- L2: 64->128 MFMA (W2B whole in cb0) ----
    {
        floatx4 acc[4][2];
        #pragma unroll
        for (int mt = 0; mt < 4; ++mt)
            #pragma unroll
            for (int nt = 0; nt < 2; ++nt) acc[mt][nt] = (floatx4)0.f;
        #pragma unroll
        for (int kc = 0; kc < 2; ++kc) {
            short8 a[4];
            #pragma unroll
            for (int mt = 0; mt < 4; ++mt)
                a[mt] = *reinterpret_cast<const short8*>(x1A + ((mt * 2 + kc) * 64 + lane) * 8);
            #pragma unroll
            for (int nt = 0; nt < 2; ++nt) {
                short8 bf = *reinterpret_cast<const short8*>(
                    cb0 + ((kc * 8 + w * 2 + nt) * 64 + lane) * 8);
                #pragma unroll
                for (int mt = 0; mt < 4; ++mt)
                    acc[mt][nt] = __builtin_amdgcn_mfma_f32_16x16x32_bf16(a[mt], bf, acc[mt][nt], 0, 0, 0);
            }
        }
        __syncthreads();                             // cb0 free
        issue_chunk16k((const char*)W3B + 16384, cb0, tid);  // W3 c1
        #pragma unroll
        for (int nt = 0; nt < 2; ++nt) {
            int c = (w * 2 + nt) * 16 + (lane & 15);
            float bb = b2[c], sc = s2v[c], tt = t2v[c];
            #pragma unroll
            for (int mt = 0; mt < 4; ++mt)
                #pragma unroll
                for (int r = 0; r < 4; ++r) {
                    int ml = (lane >> 4) * 4 + r;
                    float v = fmaxf(fmaf(acc[mt][nt][r] + bb, sc, tt), 0.f);
                    x2A[((mt * 4 + (c >> 5)) * 64 + ml + (((c >> 3) & 3) << 4)) * 8 + (c & 7)] = f2bf(v);
                }
        }
    }
    __syncthreads();                                 // x2A visible, W3c1 in

    // ---- L3: 128->256 MFMA, 4 chunks ----
    {
        floatx4 acc3[4][4];
        #pragma unroll
        for (int mt = 0; mt < 4; ++mt)
            #pragma unroll
            for (int nt = 0; nt < 4; ++nt) acc3[mt][nt] = (floatx4)0.f;
        #pragma unroll
        for (int kc = 0; kc < 4; ++kc) {
            mfma16<4>(x2A, kc, (kc & 1) ? cb0 : cb1, w, lane, acc3);
            __syncthreads();
            if (kc == 0)      issue_chunk16k((const char*)W3B + 2 * 16384, cb1, tid);
            else if (kc == 1) issue_chunk16k((const char*)W3B + 3 * 16384, cb0, tid);
            else if (kc == 2) issue_chunk16k((const char*)W4B, cb1, tid);        // W4 kc0 nh0
            else              issue_chunk16k((const char*)W4B + 32768, cb0, tid); // W4 kc1 nh0
        }
        #pragma unroll
        for (int nt = 0; nt < 4; ++nt) {
            int c = w * 64 + nt * 16 + (lane & 15);
            float bb = b3[c], sc = s3v[c], tt = t3v[c];
            #pragma unroll
            for (int mt = 0; mt < 4; ++mt)
                #pragma unroll
                for (int r = 0; r < 4; ++r) {
                    int ml = (lane >> 4) * 4 + r;
                    float v = fmaxf(fmaf(acc3[mt][nt][r] + bb, sc, tt), 0.f);
                    x3A[((mt * 8 + (c >> 5)) * 64 + ml + (((c >> 3) & 3) << 4)) * 8 + (c & 7)] = f2bf(v);
                }
        }
    }
    __syncthreads();                                 // x3A visible, W4 kc0/kc1 in

    // ---- L4: 256->512 MFMA, 2 halves x 8 chunks ----
    #pragma unroll 1
    for (int nh = 0; nh < 2; ++nh) {
        floatx4 acc4[4][4];
        #pragma unroll
        for (int mt = 0; mt < 4; ++mt)
            #pragma unroll
            for (int nt = 0; nt < 4; ++nt) acc4[mt][nt] = (floatx4)0.f;
        #pragma unroll
        for (int kc = 0; kc < 8; ++kc) {
            mfma16<8>(x3A, kc, (kc & 1) ? cb0 : cb1, w, lane, acc4);
            __syncthreads();
            if (kc < 6)
                issue_chunk16k((const char*)W4B + (size_t)(kc + 2) * 32768 + nh * 16384,
                               (kc & 1) ? cb0 : cb1, tid);
        }
        // epilogue: acc + b4 -> rep[64][256] bf16
        #pragma unroll
        for (int nt = 0; nt < 4; ++nt) {
            int cl = w * 64 + nt * 16 + (lane & 15);
            float bb = b4[nh * 256 + cl];
            #pragma unroll
            for (int mt = 0; mt < 4; ++mt)
                #pragma unroll
                for (int r = 0; r < 4; ++r) {
                    int m = mt * 16 + (lane >> 4) * 4 + r;
                    rep[m * 256 + cl] = f2bf(acc4[mt][nt][r] + bb);
                }
        }
        __syncthreads();                             // rep visible
        // copy-out: rep is [64 rows][256 cols] bf16 = 32 uint4 per row
        #pragma unroll
        for (int r = 0; r < 8; ++r) {
            int q = r * 256 + tid;                   // uint4 index, 0..2047
            int m = q >> 5, co = (q & 31) * 8;
            *reinterpret_cast<uint4*>(
                &x4out[((size_t)(b * N_ + n0 + m)) * 512 + nh * 256 + co]) =
                reinterpret_cast<const uint4*>(rep)[q];
        }
        if (nh == 0) {
            __syncthreads();                         // rep reads done, ring free
            issue_chunk16k((const char*)W4B + 16384, cb1, tid);          // kc0 nh1
            issue_chunk16k((const char*)W4B + 32768 + 16384, cb0, tid);  // kc1 nh1
            __syncthreads();                         // drained
        }
    }
}

// ---------------- per-voxel max-pool + MFMA compression (occupied only) ----
// 16 voxels/iter. Phase 1: 16 groups x 16 lanes, coalesced row loads,
// register max (lossless bf16 repack into A-fragment LDS).
// Phase 2: wave w = (khalf=w>>1, ntile=w&1), 8 MFMAs vs preloaded Wc B-frags.
__global__ __launch_bounds__(256) void k_pool(
        const int* __restrict__ head, const int* __restrict__ nxt,
        const unsigned short* __restrict__ x4,
        const unsigned short* __restrict__ WcB, const float* __restrict__ bcv,
        float* __restrict__ out, const int* __restrict__ list,
        const int* __restrict__ cnt)
{
    __shared__ __align__(16) unsigned short mxA[16 * 64 * 8];  // [kc][lane][8] 16KB
    __shared__ float part[4][256];                              // [wave][m*16+c] 4KB
    __shared__ int gidsh[16];
    int tid = threadIdx.x;
    int w = tid >> 6, lane = tid & 63;
    int kh = w >> 1, nt = w & 1;
    int g = tid >> 4, l = tid & 15;          // phase-1: group=voxel slot, lane
    int nocc = cnt[0];

    // preload Wc B-fragments (iteration-invariant): 8 short8 = 32 VGPR
    short8 breg[8];
    #pragma unroll
    for (int kk = 0; kk < 8; ++kk)
        breg[kk] = *reinterpret_cast<const short8*>(
            WcB + (size_t)(((kh * 8 + kk) * 2 + nt) * 64 + lane) * 8);

    for (int base = blockIdx.x * 16; base < nocc; base += 2048 * 16) {
        {   // ---- phase 1: chain walk + max + A-frag repack ----
            float mx[4][8];
            int idx = base + g;
            if (idx < nocc) {
                int gid = list[idx];
                if (l == 0) gidsh[g] = gid;
                #pragma unroll
                for (int i = 0; i < 4; ++i)
                    #pragma unroll
                    for (int j = 0; j < 8; ++j) mx[i][j] = -3.0e38f;
                int cur = head[gid];
                while (cur >= 0) {
                    const uint4* row = reinterpret_cast<const uint4*>(x4 + (size_t)cur * 512);
                    #pragma unroll
                    for (int i = 0; i < 4; ++i) {
                        uint4 r = row[i * 16 + l];     // ch c = i*128 + l*8 + j
                        unsigned rr[4] = {r.x, r.y, r.z, r.w};
                        #pragma unroll
                        for (int q = 0; q < 4; ++q) {
                            mx[i][2*q]   = fmaxf(mx[i][2*q],   __uint_as_float((rr[q] & 0xFFFFu) << 16));
                            mx[i][2*q+1] = fmaxf(mx[i][2*q+1], __uint_as_float(rr[q] & 0xFFFF0000u));
                        }
                    }
                    cur = nxt[cur];
                }
            } else {
                if (l == 0) gidsh[g] = -1;
                #pragma unroll
                for (int i = 0; i < 4; ++i)
                    #pragma unroll
                    for (int j = 0; j < 8; ++j) mx[i][j] = 0.f;
            }
            // repack (lossless: maxes of bf16 are bf16): octet o=i*16+l ->
            // kc = i*4 + (l>>2), hi = l&3, dest lane' = g + hi*16
            #pragma unroll
            for (int i = 0; i < 4; ++i) {
                __align__(16) unsigned short o[8];
                #pragma unroll
                for (int j = 0; j < 8; ++j) o[j] = f2bf(mx[i][j]);
                int kc = i * 4 + (l >> 2);
                int dl = g + ((l & 3) << 4);
                *reinterpret_cast<uint4*>(&mxA[(kc * 64 + dl) * 8]) =
                    *reinterpret_cast<const uint4*>(o);
            }
        }
        __syncthreads();
        {   // ---- phase 2: MFMA 16x32x512 (this wave: 8 k-chunks, 1 n-tile) ----
            floatx4 acc = (floatx4)0.f;
            #pragma unroll
            for (int kk = 0; kk < 8; ++kk) {
                short8 a = *reinterpret_cast<const short8*>(
                    &mxA[((kh * 8 + kk) * 64 + lane) * 8]);
                acc = __builtin_amdgcn_mfma_f32_16x16x32_bf16(a, breg[kk], acc, 0, 0, 0);
            }
            #pragma unroll
            for (int r = 0; r < 4; ++r)
                part[w][((lane >> 4) * 4 + r) * 16 + (lane & 15)] = acc[r];
        }
        __syncthreads();
        {   // ---- phase 2b: cross-wave K-reduce + bias + relu + scatter ----
            int m = tid & 15, n = tid >> 4;          // voxel m, channel n / n+16
            int gid = gidsh[m];
            if (gid >= 0) {
                float v0 = fmaxf(part[0][m * 16 + n] + part[2][m * 16 + n] + bcv[n], 0.f);
                float v1 = fmaxf(part[1][m * 16 + n] + part[3][m * 16 + n] + bcv[n + 16], 0.f);
                int b = gid / HWv, v = gid - b * HWv;
                int x = v / GYv, y = v - x * GYv;
                out[(((size_t)b * NHv + n)      * GXv + x) * GYv + y] = v0;
                out[(((size_t)b * NHv + n + 16) * GXv + x) * GYv + y] = v1;
            }
        }
        __syncthreads();                             // protect gidsh/mxA/part
    }
}

extern "C" void kernel_launch(void* const* d_in, const int* in_sizes, int n_in,
                              void* d_out, int out_size, void* d_ws, size_t ws_size,
                              hipStream_t stream) {
    const float* pt_fea = (const float*)d_in[0];
    const int*   xy     = (const int*)d_in[1];
    const float* s0v = (const float*)d_in[2];  const float* t0v = (const float*)d_in[3];
    const float* s1v = (const float*)d_in[4];  const float* t1v = (const float*)d_in[5];
    const float* s2v = (const float*)d_in[6];  const float* t2v = (const float*)d_in[7];
    const float* s3v = (const float*)d_in[8];  const float* t3v = (const float*)d_in[9];
    const float* W1  = (const float*)d_in[10]; const float* b1  = (const float*)d_in[11];
    const float* W2  = (const float*)d_in[12]; const float* b2  = (const float*)d_in[13];
    const float* W3  = (const float*)d_in[14]; const float* b3  = (const float*)d_in[15];
    const float* W4  = (const float*)d_in[16]; const float* b4  = (const float*)d_in[17];
    const float* Wc  = (const float*)d_in[18]; const float* bc  = (const float*)d_in[19];

    // workspace: x4 | head | nxt | list | cnt | W2B | W3B | W4B | WcB
    char* ws = (char*)d_ws;
    size_t off = 0;
    unsigned short* x4   = (unsigned short*)(ws + off); off += (size_t)B_ * N_ * 512 * 2;
    int* head            = (int*)(ws + off);            off += (size_t)B_ * HWv * 4;
    int* nxt             = (int*)(ws + off);            off += (size_t)B_ * N_ * 4;
    int* list            = (int*)(ws + off);            off += (size_t)B_ * N_ * 4;
    int* cnt             = (int*)(ws + off);            off += 256;
    unsigned short* W2B  = (unsigned short*)(ws + off); off += 64 * 128 * 2;
    unsigned short* W3B  = (unsigned short*)(ws + off); off += 128 * 256 * 2;
    unsigned short* W4B  = (unsigned short*)(ws + off); off += 256 * 512 * 2;
    unsigned short* WcB  = (unsigned short*)(ws + off); off += 512 * 32 * 2;

    hipLaunchKernelGGL(k_init_head, dim3(1350),  dim3(256), 0, stream, head, cnt);
    hipLaunchKernelGGL(k_zero_out,  dim3(10800), dim3(256), 0, stream, (uint4*)d_out);
    hipLaunchKernelGGL(k_chain,     dim3(512),   dim3(256), 0, stream, xy, head, nxt, list, cnt);
    hipLaunchKernelGGL(k_cvtB,      dim3(4),     dim3(256), 0, stream, W2, W2B, 64, 128);
    hipLaunchKernelGGL(k_cvtB,      dim3(16),    dim3(256), 0, stream, W3, W3B, 128, 256);
    hipLaunchKernelGGL(k_cvtB,      dim3(64),    dim3(256), 0, stream, W4, W4B, 256, 512);
    hipLaunchKernelGGL(k_cvtB,      dim3(8),     dim3(256), 0, stream, Wc, WcB, 512, 32);
    hipLaunchKernelGGL(k_mlp,       dim3(2048),  dim3(256), 0, stream,
        pt_fea, s0v, t0v, s1v, t1v, s2v, t2v, s3v, t3v,
        W1, b1, W2B, b2, W3B, b3, W4B, b4, x4);
    hipLaunchKernelGGL(k_pool,      dim3(2048),  dim3(256), 0, stream,
        head, nxt, x4, WcB, bc, (float*)d_out, list, cnt);
}

// Round 8
// 194.788 us; speedup vs baseline: 5.6514x; 1.0099x over previous
//
#include <hip/hip_runtime.h>
#include <cstdint>
#include <cstddef>

#define B_   2
#define N_   65536
#define GXv  480
#define GYv  360
#define NHv  32
#define HWv  (GXv*GYv)          // 172800

typedef __attribute__((ext_vector_type(8))) short short8;
typedef __attribute__((ext_vector_type(4))) float floatx4;

// round-to-nearest-even f32 -> bf16
__device__ __forceinline__ unsigned short f2bf(float f) {
    unsigned u = __float_as_uint(f);
    u += 0x7FFFu + ((u >> 16) & 1u);
    return (unsigned short)(u >> 16);
}

// async global->LDS, 16B per lane (dest linear base + tid*16, lane-contiguous)
__device__ __forceinline__ void issue16(const void* g, void* l) {
    __builtin_amdgcn_global_load_lds(
        (const __attribute__((address_space(1))) unsigned int*)g,
        (__attribute__((address_space(3))) unsigned int*)l, 16, 0, 0);
}
__device__ __forceinline__ void issue_chunk16k(const void* g, void* l, int tid) {
    #pragma unroll
    for (int i = 0; i < 4; ++i)
        issue16((const char*)g + tid * 16 + i * 4096,
                (char*)l + tid * 16 + i * 4096);
}

// ---- counted-vmcnt phase barriers (T4): one chunk = 4 loads/thread ----
// phase top: the chunk we are about to consume is landed; ONE younger chunk
// (4 loads) may stay in flight across the barrier.
__device__ __forceinline__ void phase_top4() {
    asm volatile("s_waitcnt vmcnt(4) lgkmcnt(0)" ::: "memory");
    __builtin_amdgcn_s_barrier();
    __builtin_amdgcn_sched_barrier(0);
}
__device__ __forceinline__ void phase_top0() {
    asm volatile("s_waitcnt vmcnt(0) lgkmcnt(0)" ::: "memory");
    __builtin_amdgcn_s_barrier();
    __builtin_amdgcn_sched_barrier(0);
}
// post-compute barrier: own LDS ops retired, then all-wave barrier
__device__ __forceinline__ void lds_bar() {
    asm volatile("s_waitcnt lgkmcnt(0)" ::: "memory");
    __builtin_amdgcn_s_barrier();
    __builtin_amdgcn_sched_barrier(0);
}

// ---------------- init / zero ----------------
__global__ void k_init_head(int* head, int* cnt) {
    int i = blockIdx.x * 256 + threadIdx.x;
    if (i < B_ * HWv) head[i] = -1;
    if (i == 0) cnt[0] = 0;
}
__global__ void k_zero_out(uint4* out) {
    int i = blockIdx.x * 256 + threadIdx.x;
    if (i < (B_ * NHv * HWv * 4) / 16) out[i] = make_uint4(0, 0, 0, 0);
}

// ---------------- voxel bucketing + occupied-voxel compaction ----------------
// Chain/list order is atomic-nondeterministic, but max-pool is commutative and
// each voxel writes only its own output location -> output deterministic.
// (keep-cap MAX_PT=256 never triggers: 65536 pts over 129600 voxels.)
__global__ void k_chain(const int* __restrict__ xy, int* head, int* nxt,
                        int* list, int* cnt) {
    int i = blockIdx.x * 256 + threadIdx.x;
    if (i >= B_ * N_) return;
    int b = i >> 16;
    int x = xy[2 * i], y = xy[2 * i + 1];
    int hidx = b * HWv + x * GYv + y;
    int prev = atomicExch(&head[hidx], i);
    nxt[i] = prev;
    if (prev == -1) { int s = atomicAdd(cnt, 1); list[s] = hidx; }
}

// ---------------- weight -> bf16 B-fragment-linear ----------------
// dst[((kc*NT + nt)*64 + l)*8 + j] = bf16(W[(kc*32 + (l>>4)*8 + j)*N + nt*16 + (l&15)])
__global__ void k_cvtB(const float* __restrict__ W, unsigned short* __restrict__ dst,
                       int K, int N) {
    int d = blockIdx.x * 256 + threadIdx.x;
    if (d >= (K * N) / 8) return;
    int l = d & 63;
    int g = d >> 6;
    int NT = N >> 4;
    int kc = g / NT, nt = g - kc * NT;
    int k0 = kc * 32 + (l >> 4) * 8, n = nt * 16 + (l & 15);
    __align__(16) unsigned short o[8];
    #pragma unroll
    for (int j = 0; j < 8; ++j) o[j] = f2bf(W[(size_t)(k0 + j) * N + n]);
    *reinterpret_cast<uint4*>(dst + (size_t)d * 8) = *reinterpret_cast<const uint4*>(o);
}

// 16 MFMAs: one chunk (K=32, wave's 4 n-tiles), acc[4 mt][4 nt]
template<int KC>
__device__ __forceinline__ void mfma16(const unsigned short* xA, int kc,
        const unsigned short* cc, int w, int lane, floatx4 (&acc)[4][4]) {
    short8 a[4];
    #pragma unroll
    for (int mt = 0; mt < 4; ++mt)
        a[mt] = *reinterpret_cast<const short8*>(xA + ((mt * KC + kc) * 64 + lane) * 8);
    #pragma unroll
    for (int nt = 0; nt < 4; ++nt) {
        short8 bf = *reinterpret_cast<const short8*>(cc + ((w * 4 + nt) * 64 + lane) * 8);
        #pragma unroll
        for (int mt = 0; mt < 4; ++mt)
            acc[mt][nt] = __builtin_amdgcn_mfma_f32_16x16x32_bf16(a[mt], bf, acc[mt][nt], 0, 0, 0);
    }
}

// ---------------- fused point MLP, all-MFMA, counted-vmcnt pipeline ----------
__global__ __launch_bounds__(256) void k_mlp(
        const float* __restrict__ pt_fea,
        const float* __restrict__ s0v, const float* __restrict__ t0v,
        const float* __restrict__ s1v, const float* __restrict__ t1v,
        const float* __restrict__ s2v, const float* __restrict__ t2v,
        const float* __restrict__ s3v, const float* __restrict__ t3v,
        const float* __restrict__ W1, const float* __restrict__ b1,
        const unsigned short* __restrict__ W2B, const float* __restrict__ b2,
        const unsigned short* __restrict__ W3B, const float* __restrict__ b3,
        const unsigned short* __restrict__ W4B, const float* __restrict__ b4,
        unsigned short* __restrict__ x4out)
{
    __shared__ __align__(16) char smem[65536];
    unsigned short* x1A = (unsigned short*)smem;
    unsigned short* x2A = (unsigned short*)(smem + 8192);
    unsigned short* x3A = (unsigned short*)smem;
    float*          x0s = (float*)(smem + 8192);
    unsigned short* cb0 = (unsigned short*)(smem + 32768);
    unsigned short* cb1 = (unsigned short*)(smem + 49152);
    unsigned short* rep = (unsigned short*)(smem + 32768);   // 32 rows x 272 u16

    int tid = threadIdx.x;
    int w = tid >> 6, lane = tid & 63;
    int bid = blockIdx.x;                    // 2048 blocks
    int b = bid >> 10, n0 = (bid & 1023) << 6;
    const float* fea = pt_fea + ((size_t)(b * N_ + n0)) * 9;

    issue_chunk16k(W2B, cb0, tid);           // W2 whole (16KB)
    for (int idx = tid; idx < 576; idx += 256) {
        int kk = idx % 9;
        x0s[idx] = fea[idx] * s0v[kk] + t0v[kk];
    }
    __syncthreads();                         // full drain: x0 + W2B ready

    // ---- L1: 9->64 vector f32, writes x1A (A-frag bf16, KC=2) ----
    {
        int p = tid & 63, q = tid >> 6;
        float a0[9];
        #pragma unroll
        for (int k = 0; k < 9; ++k) a0[k] = x0s[p * 9 + k];
        float acc1[16];
        #pragma unroll
        for (int c = 0; c < 16; ++c) acc1[c] = 0.f;
        #pragma unroll
        for (int k = 0; k < 9; ++k) {
            #pragma unroll
            for (int c4 = 0; c4 < 4; ++c4) {
                float4 wv = *reinterpret_cast<const float4*>(&W1[k * 64 + q * 16 + c4 * 4]);
                acc1[c4*4+0] = fmaf(a0[k], wv.x, acc1[c4*4+0]);
                acc1[c4*4+1] = fmaf(a0[k], wv.y, acc1[c4*4+1]);
                acc1[c4*4+2] = fmaf(a0[k], wv.z, acc1[c4*4+2]);
                acc1[c4*4+3] = fmaf(a0[k], wv.w, acc1[c4*4+3]);
            }
        }
        #pragma unroll
        for (int h = 0; h < 2; ++h) {
            __align__(16) unsigned short o[8];
            #pragma unroll
            for (int j = 0; j < 8; ++j) {
                int c = q * 16 + h * 8 + j;
                o[j] = f2bf(fmaxf(fmaf(acc1[h * 8 + j] + b1[c], s1v[c], t1v[c]), 0.f));
            }
            int lane2 = (p & 15) + (((q & 1) * 2 + h) << 4);
            *reinterpret_cast<uint4*>(x1A + (((p >> 4) * 2 + (q >> 1)) * 64 + lane2) * 8) =
                *reinterpret_cast<const uint4*>(o);
        }
    }
    issue_chunk16k((const char*)W3B, cb1, tid);      // W3 c0
    __syncthreads();                                 // full drain: x1A + W3c0 ready

    // ---- L2: 64->128 MFMA (W2B whole in cb0) ----
    {
        floatx4 acc[4][2];
        #pragma unroll
        for (int mt = 0; mt < 4; ++mt)
            #pragma unroll
            for (int nt = 0; nt < 2; ++nt) acc[mt][nt] = (floatx4)0.f;
        #pragma unroll
        for (int kc = 0; kc < 2; ++kc) {
            short8 a[4];
            #pragma unroll
            for (int mt = 0; mt < 4; ++mt)
                a[mt] = *reinterpret_cast<const short8*>(x1A + ((mt * 2 + kc) * 64 + lane) * 8);
            #pragma unroll
            for (int nt = 0; nt < 2; ++nt) {
                short8 bf = *reinterpret_cast<const short8*>(
                    cb0 + ((kc * 8 + w * 2 + nt) * 64 + lane) * 8);
                #pragma unroll
                for (int mt = 0; mt < 4; ++mt)
                    acc[mt][nt] = __builtin_amdgcn_mfma_f32_16x16x32_bf16(a[mt], bf, acc[mt][nt], 0, 0, 0);
            }
        }
        lds_bar();                                   // cb0 free (no vmcnt drain)
        issue_chunk16k((const char*)W3B + 16384, cb0, tid);  // W3 c1  [out=4]
        #pragma unroll
        for (int nt = 0; nt < 2; ++nt) {
            int c = (w * 2 + nt) * 16 + (lane & 15);
            float bb = b2[c], sc = s2v[c], tt = t2v[c];
            #pragma unroll
            for (int mt = 0; mt < 4; ++mt)
                #pragma unroll
                for (int r = 0; r < 4; ++r) {
                    int ml = (lane >> 4) * 4 + r;
                    float v = fmaxf(fmaf(acc[mt][nt][r] + bb, sc, tt), 0.f);
                    x2A[((mt * 4 + (c >> 5)) * 64 + ml + (((c >> 3) & 3) << 4)) * 8 + (c & 7)] = f2bf(v);
                }
        }
    }
    // (x2A made visible by L3 kc=0 phase_top)

    // ---- L3: 128->256 MFMA, 4 phases, counted-vmcnt ----
    {
        floatx4 acc3[4][4];
        #pragma unroll
        for (int mt = 0; mt < 4; ++mt)
            #pragma unroll
            for (int nt = 0; nt < 4; ++nt) acc3[mt][nt] = (floatx4)0.f;
        #pragma unroll
        for (int kc = 0; kc < 4; ++kc) {
            phase_top4();                    // chunk kc landed; next may fly
            mfma16<4>(x2A, kc, (kc & 1) ? cb0 : cb1, w, lane, acc3);
            lds_bar();                       // buffer free for re-fill
            if (kc == 0)      issue_chunk16k((const char*)W3B + 2 * 16384, cb1, tid);
            else if (kc == 1) issue_chunk16k((const char*)W3B + 3 * 16384, cb0, tid);
            else if (kc == 2) issue_chunk16k((const char*)W4B, cb1, tid);        // W4 kc0 nh0
            else              issue_chunk16k((const char*)W4B + 32768, cb0, tid); // W4 kc1 nh0
        }
        #pragma unroll
        for (int nt = 0; nt < 4; ++nt) {
            int c = w * 64 + nt * 16 + (lane & 15);
            float bb = b3[c], sc = s3v[c], tt = t3v[c];
            #pragma unroll
            for (int mt = 0; mt < 4; ++mt)
                #pragma unroll
                for (int r = 0; r < 4; ++r) {
                    int ml = (lane >> 4) * 4 + r;
                    float v = fmaxf(fmaf(acc3[mt][nt][r] + bb, sc, tt), 0.f);
                    x3A[((mt * 8 + (c >> 5)) * 64 + ml + (((c >> 3) & 3) << 4)) * 8 + (c & 7)] = f2bf(v);
                }
        }
    }
    // (x3A made visible by L4 kc=0 phase_top)

    // ---- L4: 256->512 MFMA, 2 halves x 8 phases, counted-vmcnt ----
    #pragma unroll 1
    for (int nh = 0; nh < 2; ++nh) {
        floatx4 acc4[4][4];
        #pragma unroll
        for (int mt = 0; mt < 4; ++mt)
            #pragma unroll
            for (int nt = 0; nt < 4; ++nt) acc4[mt][nt] = (floatx4)0.f;
        #pragma unroll
        for (int kc = 0; kc < 8; ++kc) {
            if (kc < 7) phase_top4(); else phase_top0();
            mfma16<8>(x3A, kc, (kc & 1) ? cb0 : cb1, w, lane, acc4);
            lds_bar();
            if (kc < 6)
                issue_chunk16k((const char*)W4B + (size_t)(kc + 2) * 32768 + nh * 16384,
                               (kc & 1) ? cb0 : cb1, tid);
        }
        // epilogue: two 32-row halves, rep stride 272 (conflict-free u16 writes)
        #pragma unroll
        for (int mh = 0; mh < 2; ++mh) {
            #pragma unroll
            for (int nt = 0; nt < 4; ++nt) {
                int cl = w * 64 + nt * 16 + (lane & 15);
                float bb = b4[nh * 256 + cl];
                #pragma unroll
                for (int mt2 = 0; mt2 < 2; ++mt2) {
                    int mt = mh * 2 + mt2;
                    #pragma unroll
                    for (int r = 0; r < 4; ++r) {
                        int ml = mt2 * 16 + (lane >> 4) * 4 + r;
                        rep[ml * 272 + cl] = f2bf(acc4[mt][nt][r] + bb);
                    }
                }
            }
            lds_bar();                               // rep half visible
            #pragma unroll
            for (int r2 = 0; r2 < 4; ++r2) {
                int q = r2 * 256 + tid;              // uint4 index, 0..1023
                int m = q >> 5, co = (q & 31) * 8;
                *reinterpret_cast<uint4*>(
                    &x4out[((size_t)(b * N_ + n0 + mh * 32 + m)) * 512 + nh * 256 + co]) =
                    *reinterpret_cast<const uint4*>(rep + m * 272 + co);
            }
            lds_bar();                               // rep free
        }
        if (nh == 0) {
            issue_chunk16k((const char*)W4B + 16384, cb1, tid);          // kc0 nh1
            issue_chunk16k((const char*)W4B + 32768 + 16384, cb0, tid);  // kc1 nh1
        }
    }
}

// ---------------- per-voxel max-pool + MFMA compression (occupied only) ----
__global__ __launch_bounds__(256) void k_pool(
        const int* __restrict__ head, const int* __restrict__ nxt,
        const unsigned short* __restrict__ x4,
        const unsigned short* __restrict__ WcB, const float* __restrict__ bcv,
        float* __restrict__ out, const int* __restrict__ list,
        const int* __restrict__ cnt)
{
    __shared__ __align__(16) unsigned short mxA[16 * 64 * 8];  // [kc][lane][8] 16KB
    __shared__ float part[4][256];                              // [wave][m*16+c] 4KB
    __shared__ int gidsh[16];
    int tid = threadIdx.x;
    int w = tid >> 6, lane = tid & 63;
    int kh = w >> 1, nt = w & 1;
    int g = tid >> 4, l = tid & 15;          // phase-1: group=voxel slot, lane
    int nocc = cnt[0];

    // preload Wc B-fragments (iteration-invariant): 8 short8 = 32 VGPR
    short8 breg[8];
    #pragma unroll
    for (int kk = 0; kk < 8; ++kk)
        breg[kk] = *reinterpret_cast<const short8*>(
            WcB + (size_t)(((kh * 8 + kk) * 2 + nt) * 64 + lane) * 8);

    for (int base = blockIdx.x * 16; base < nocc; base += 2048 * 16) {
        {   // ---- phase 1: chain walk + max + A-frag repack ----
            float mx[4][8];
            int idx = base + g;
            if (idx < nocc) {
                int gid = list[idx];
                if (l == 0) gidsh[g] = gid;
                #pragma unroll
                for (int i = 0; i < 4; ++i)
                    #pragma unroll
                    for (int j = 0; j < 8; ++j) mx[i][j] = -3.0e38f;
                int cur = head[gid];
                while (cur >= 0) {
                    const uint4* row = reinterpret_cast<const uint4*>(x4 + (size_t)cur * 512);
                    #pragma unroll
                    for (int i = 0; i < 4; ++i) {
                        uint4 r = row[i * 16 + l];     // ch c = i*128 + l*8 + j
                        unsigned rr[4] = {r.x, r.y, r.z, r.w};
                        #pragma unroll
                        for (int q = 0; q < 4; ++q) {
                            mx[i][2*q]   = fmaxf(mx[i][2*q],   __uint_as_float((rr[q] & 0xFFFFu) << 16));
                            mx[i][2*q+1] = fmaxf(mx[i][2*q+1], __uint_as_float(rr[q] & 0xFFFF0000u));
                        }
                    }
                    cur = nxt[cur];
                }
            } else {
                if (l == 0) gidsh[g] = -1;
                #pragma unroll
                for (int i = 0; i < 4; ++i)
                    #pragma unroll
                    for (int j = 0; j < 8; ++j) mx[i][j] = 0.f;
            }
            // repack (lossless: maxes of bf16 are bf16): octet o=i*16+l ->
            // kc = i*4 + (l>>2), hi = l&3, dest lane' = g + hi*16
            #pragma unroll
            for (int i = 0; i < 4; ++i) {
                __align__(16) unsigned short o[8];
                #pragma unroll
                for (int j = 0; j < 8; ++j) o[j] = f2bf(mx[i][j]);
                int kc = i * 4 + (l >> 2);
                int dl = g + ((l & 3) << 4);
                *reinterpret_cast<uint4*>(&mxA[(kc * 64 + dl) * 8]) =
                    *reinterpret_cast<const uint4*>(o);
            }
        }
        __syncthreads();
        {   // ---- phase 2: MFMA 16x32x512 (this wave: 8 k-chunks, 1 n-tile) ----
            floatx4 acc = (floatx4)0.f;
            #pragma unroll
            for (int kk = 0; kk < 8; ++kk) {
                short8 a = *reinterpret_cast<const short8*>(
                    &mxA[((kh * 8 + kk) * 64 + lane) * 8]);
                acc = __builtin_amdgcn_mfma_f32_16x16x32_bf16(a, breg[kk], acc, 0, 0, 0);
            }
            #pragma unroll
            for (int r = 0; r < 4; ++r)
                part[w][((lane >> 4) * 4 + r) * 16 + (lane & 15)] = acc[r];
        }
        __syncthreads();
        {   // ---- phase 2b: cross-wave K-reduce + bias + relu + scatter ----
            int m = tid & 15, n = tid >> 4;          // voxel m, channel n / n+16
            int gid = gidsh[m];
            if (gid >= 0) {
                float v0 = fmaxf(part[0][m * 16 + n] + part[2][m * 16 + n] + bcv[n], 0.f);
                float v1 = fmaxf(part[1][m * 16 + n] + part[3][m * 16 + n] + bcv[n + 16], 0.f);
                int b = gid / HWv, v = gid - b * HWv;
                int x = v / GYv, y = v - x * GYv;
                out[(((size_t)b * NHv + n)      * GXv + x) * GYv + y] = v0;
                out[(((size_t)b * NHv + n + 16) * GXv + x) * GYv + y] = v1;
            }
        }
        __syncthreads();                             // protect gidsh/mxA/part
    }
}

extern "C" void kernel_launch(void* const* d_in, const int* in_sizes, int n_in,
                              void* d_out, int out_size, void* d_ws, size_t ws_size,
                              hipStream_t stream) {
    const float* pt_fea = (const float*)d_in[0];
    const int*   xy     = (const int*)d_in[1];
    const float* s0v = (const float*)d_in[2];  const float* t0v = (const float*)d_in[3];
    const float* s1v = (const float*)d_in[4];  const float* t1v = (const float*)d_in[5];
    const float* s2v = (const float*)d_in[6];  const float* t2v = (const float*)d_in[7];
    const float* s3v = (const float*)d_in[8];  const float* t3v = (const float*)d_in[9];
    const float* W1  = (const float*)d_in[10]; const float* b1  = (const float*)d_in[11];
    const float* W2  = (const float*)d_in[12]; const float* b2  = (const float*)d_in[13];
    const float* W3  = (const float*)d_in[14]; const float* b3  = (const float*)d_in[15];
    const float* W4  = (const float*)d_in[16]; const float* b4  = (const float*)d_in[17];
    const float* Wc  = (const float*)d_in[18]; const float* bc  = (const float*)d_in[19];

    // workspace: x4 | head | nxt | list | cnt | W2B | W3B | W4B | WcB
    char* ws = (char*)d_ws;
    size_t off = 0;
    unsigned short* x4   = (unsigned short*)(ws + off); off += (size_t)B_ * N_ * 512 * 2;
    int* head            = (int*)(ws + off);            off += (size_t)B_ * HWv * 4;
    int* nxt             = (int*)(ws + off);            off += (size_t)B_ * N_ * 4;
    int* list            = (int*)(ws + off);            off += (size_t)B_ * N_ * 4;
    int* cnt             = (int*)(ws + off);            off += 256;
    unsigned short* W2B  = (unsigned short*)(ws + off); off += 64 * 128 * 2;
    unsigned short* W3B  = (unsigned short*)(ws + off); off += 128 * 256 * 2;
    unsigned short* W4B  = (unsigned short*)(ws + off); off += 256 * 512 * 2;
    unsigned short* WcB  = (unsigned short*)(ws + off); off += 512 * 32 * 2;

    hipLaunchKernelGGL(k_init_head, dim3(1350),  dim3(256), 0, stream, head, cnt);
    hipLaunchKernelGGL(k_zero_out,  dim3(10800), dim3(256), 0, stream, (uint4*)d_out);
    hipLaunchKernelGGL(k_chain,     dim3(512),   dim3(256), 0, stream, xy, head, nxt, list, cnt);
    hipLaunchKernelGGL(k_cvtB,      dim3(4),     dim3(256), 0, stream, W2, W2B, 64, 128);
    hipLaunchKernelGGL(k_cvtB,      dim3(16),    dim3(256), 0, stream, W3, W3B, 128, 256);
    hipLaunchKernelGGL(k_cvtB,      dim3(64),    dim3(256), 0, stream, W4, W4B, 256, 512);
    hipLaunchKernelGGL(k_cvtB,      dim3(8),     dim3(256), 0, stream, Wc, WcB, 512, 32);
    hipLaunchKernelGGL(k_mlp,       dim3(2048),  dim3(256), 0, stream,
        pt_fea, s0v, t0v, s1v, t1v, s2v, t2v, s3v, t3v,
        W1, b1, W2B, b2, W3B, b3, W4B, b4, x4);
    hipLaunchKernelGGL(k_pool,      dim3(2048),  dim3(256), 0, stream,
        head, nxt, x4, WcB, bc, (float*)d_out, list, cnt);
}

// Round 9
// 186.521 us; speedup vs baseline: 5.9019x; 1.0443x over previous
//
#include <hip/hip_runtime.h>
#include <cstdint>
#include <cstddef>

#define B_   2
#define N_   65536
#define GXv  480
#define GYv  360
#define NHv  32
#define HWv  (GXv*GYv)          // 172800

typedef __attribute__((ext_vector_type(8))) short short8;
typedef __attribute__((ext_vector_type(4))) float floatx4;

// round-to-nearest-even f32 -> bf16
__device__ __forceinline__ unsigned short f2bf(float f) {
    unsigned u = __float_as_uint(f);
    u += 0x7FFFu + ((u >> 16) & 1u);
    return (unsigned short)(u >> 16);
}

// ---------------- init / zero ----------------
__global__ void k_init_head(int* head, int* cnt) {
    int i = blockIdx.x * 256 + threadIdx.x;
    if (i < B_ * HWv) head[i] = -1;
    if (i == 0) cnt[0] = 0;
}
__global__ void k_zero_out(uint4* out) {
    int i = blockIdx.x * 256 + threadIdx.x;
    if (i < (B_ * NHv * HWv * 4) / 16) out[i] = make_uint4(0, 0, 0, 0);
}

// ---------------- voxel bucketing + occupied-voxel compaction ----------------
// Chain/list order is atomic-nondeterministic, but max-pool is commutative and
// each voxel writes only its own output location -> output deterministic.
// (keep-cap MAX_PT=256 never triggers: 65536 pts over 129600 voxels.)
__global__ void k_chain(const int* __restrict__ xy, int* head, int* nxt,
                        int* list, int* cnt) {
    int i = blockIdx.x * 256 + threadIdx.x;
    if (i >= B_ * N_) return;
    int b = i >> 16;
    int x = xy[2 * i], y = xy[2 * i + 1];
    int hidx = b * HWv + x * GYv + y;
    int prev = atomicExch(&head[hidx], i);
    nxt[i] = prev;
    if (prev == -1) { int s = atomicAdd(cnt, 1); list[s] = hidx; }
}

// ---------------- weight -> bf16 B-fragment-linear ----------------
// dst[((kc*NT + nt)*64 + l)*8 + j] = bf16(W[(kc*32 + (l>>4)*8 + j)*N + nt*16 + (l&15)])
__global__ void k_cvtB(const float* __restrict__ W, unsigned short* __restrict__ dst,
                       int K, int N) {
    int d = blockIdx.x * 256 + threadIdx.x;
    if (d >= (K * N) / 8) return;
    int l = d & 63;
    int g = d >> 6;
    int NT = N >> 4;
    int kc = g / NT, nt = g - kc * NT;
    int k0 = kc * 32 + (l >> 4) * 8, n = nt * 16 + (l & 15);
    __align__(16) unsigned short o[8];
    #pragma unroll
    for (int j = 0; j < 8; ++j) o[j] = f2bf(W[(size_t)(k0 + j) * N + n]);
    *reinterpret_cast<uint4*>(dst + (size_t)d * 8) = *reinterpret_cast<const uint4*>(o);
}

// ---------------- fused point MLP: A in LDS, B global->VGPR prefetch --------
// 64-pt tiles, 4 waves, 48KB LDS arena -> 3 blocks/CU:
//   [0,8K)=x1A ; [0,32K)=x3A (clobbers x1A at L3 epi, after barrier)
//   [32K,48K)=x2A ; x0s + rep alias the same region (lifetimes disjoint)
__global__ __launch_bounds__(256, 3) void k_mlp(
        const float* __restrict__ pt_fea,
        const float* __restrict__ s0v, const float* __restrict__ t0v,
        const float* __restrict__ s1v, const float* __restrict__ t1v,
        const float* __restrict__ s2v, const float* __restrict__ t2v,
        const float* __restrict__ s3v, const float* __restrict__ t3v,
        const float* __restrict__ W1, const float* __restrict__ b1,
        const unsigned short* __restrict__ W2B, const float* __restrict__ b2,
        const unsigned short* __restrict__ W3B, const float* __restrict__ b3,
        const unsigned short* __restrict__ W4B, const float* __restrict__ b4,
        unsigned short* __restrict__ x4out)
{
    __shared__ __align__(16) char smem[49152];
    unsigned short* x1A = (unsigned short*)smem;              // [0,8K)
    unsigned short* x3A = (unsigned short*)smem;              // [0,32K)
    unsigned short* x2A = (unsigned short*)(smem + 32768);    // [32K,48K)
    float*          x0s = (float*)(smem + 32768);             // [32K,+2.25K)
    unsigned short* rep = (unsigned short*)(smem + 32768);    // [32K,48K)

    const short8* W2v = reinterpret_cast<const short8*>(W2B);
    const short8* W3v = reinterpret_cast<const short8*>(W3B);
    const short8* W4v = reinterpret_cast<const short8*>(W4B);

    int tid = threadIdx.x;
    int w = tid >> 6, lane = tid & 63;
    int bid = blockIdx.x;                    // 2048 blocks
    int b = bid >> 10, n0 = (bid & 1023) << 6;
    const float* fea = pt_fea + ((size_t)(b * N_ + n0)) * 9;

    for (int idx = tid; idx < 576; idx += 256) {
        int kk = idx % 9;
        x0s[idx] = fea[idx] * s0v[kk] + t0v[kk];
    }
    // L2 B-fragments: 4 regs-resident frags (issued early, latency hidden)
    short8 b2r[2][2];
    #pragma unroll
    for (int kc = 0; kc < 2; ++kc)
        #pragma unroll
        for (int t = 0; t < 2; ++t)
            b2r[kc][t] = W2v[(kc * 8 + w * 2 + t) * 64 + lane];
    __syncthreads();                         // x0 ready

    // ---- L1: 9->64 vector f32, writes x1A (A-frag bf16, KC=2) ----
    {
        int p = tid & 63, q = tid >> 6;
        float a0[9];
        #pragma unroll
        for (int k = 0; k < 9; ++k) a0[k] = x0s[p * 9 + k];
        float acc1[16];
        #pragma unroll
        for (int c = 0; c < 16; ++c) acc1[c] = 0.f;
        #pragma unroll
        for (int k = 0; k < 9; ++k) {
            #pragma unroll
            for (int c4 = 0; c4 < 4; ++c4) {
                float4 wv = *reinterpret_cast<const float4*>(&W1[k * 64 + q * 16 + c4 * 4]);
                acc1[c4*4+0] = fmaf(a0[k], wv.x, acc1[c4*4+0]);
                acc1[c4*4+1] = fmaf(a0[k], wv.y, acc1[c4*4+1]);
                acc1[c4*4+2] = fmaf(a0[k], wv.z, acc1[c4*4+2]);
                acc1[c4*4+3] = fmaf(a0[k], wv.w, acc1[c4*4+3]);
            }
        }
        #pragma unroll
        for (int h = 0; h < 2; ++h) {
            __align__(16) unsigned short o[8];
            #pragma unroll
            for (int j = 0; j < 8; ++j) {
                int c = q * 16 + h * 8 + j;
                o[j] = f2bf(fmaxf(fmaf(acc1[h * 8 + j] + b1[c], s1v[c], t1v[c]), 0.f));
            }
            int lane2 = (p & 15) + (((q & 1) * 2 + h) << 4);
            *reinterpret_cast<uint4*>(x1A + (((p >> 4) * 2 + (q >> 1)) * 64 + lane2) * 8) =
                *reinterpret_cast<const uint4*>(o);
        }
    }
    __syncthreads();                         // x1A visible

    // ---- L2: 64->128 MFMA, B in regs ----
    {
        floatx4 acc2[4][2];
        #pragma unroll
        for (int mt = 0; mt < 4; ++mt)
            #pragma unroll
            for (int nt = 0; nt < 2; ++nt) acc2[mt][nt] = (floatx4)0.f;
        #pragma unroll
        for (int kc = 0; kc < 2; ++kc) {
            short8 a[4];
            #pragma unroll
            for (int mt = 0; mt < 4; ++mt)
                a[mt] = *reinterpret_cast<const short8*>(x1A + ((mt * 2 + kc) * 64 + lane) * 8);
            #pragma unroll
            for (int nt = 0; nt < 2; ++nt)
                #pragma unroll
                for (int mt = 0; mt < 4; ++mt)
                    acc2[mt][nt] = __builtin_amdgcn_mfma_f32_16x16x32_bf16(
                        a[mt], b2r[kc][nt], acc2[mt][nt], 0, 0, 0);
        }
        // epilogue -> x2A (region's x0s reads finished before the x1A barrier)
        #pragma unroll
        for (int nt = 0; nt < 2; ++nt) {
            int c = (w * 2 + nt) * 16 + (lane & 15);
            float bb = b2[c], sc = s2v[c], tt = t2v[c];
            #pragma unroll
            for (int mt = 0; mt < 4; ++mt)
                #pragma unroll
                for (int r = 0; r < 4; ++r) {
                    int ml = (lane >> 4) * 4 + r;
                    float v = fmaxf(fmaf(acc2[mt][nt][r] + bb, sc, tt), 0.f);
                    x2A[((mt * 4 + (c >> 5)) * 64 + ml + (((c >> 3) & 3) << 4)) * 8 + (c & 7)] = f2bf(v);
                }
        }
    }
    // prefetch L3 kc=0 B-frags
    short8 bb3[2][4];
    #pragma unroll
    for (int t = 0; t < 4; ++t) bb3[0][t] = W3v[(w * 4 + t) * 64 + lane];
    __syncthreads();                         // x2A visible

    // ---- L3: 128->256 MFMA, 4 kc, B ping-pong prefetch ----
    {
        floatx4 acc3[4][4];
        #pragma unroll
        for (int mt = 0; mt < 4; ++mt)
            #pragma unroll
            for (int nt = 0; nt < 4; ++nt) acc3[mt][nt] = (floatx4)0.f;
        #pragma unroll
        for (int kc = 0; kc < 4; ++kc) {
            if (kc < 3) {
                #pragma unroll
                for (int t = 0; t < 4; ++t)
                    bb3[(kc + 1) & 1][t] = W3v[((kc + 1) * 16 + w * 4 + t) * 64 + lane];
            }
            short8 a[4];
            #pragma unroll
            for (int mt = 0; mt < 4; ++mt)
                a[mt] = *reinterpret_cast<const short8*>(x2A + ((mt * 4 + kc) * 64 + lane) * 8);
            #pragma unroll
            for (int nt = 0; nt < 4; ++nt)
                #pragma unroll
                for (int mt = 0; mt < 4; ++mt)
                    acc3[mt][nt] = __builtin_amdgcn_mfma_f32_16x16x32_bf16(
                        a[mt], bb3[kc & 1][nt], acc3[mt][nt], 0, 0, 0);
        }
        // epilogue -> x3A ([0,32K); x1A reads all ended before x2A barrier)
        #pragma unroll
        for (int nt = 0; nt < 4; ++nt) {
            int c = w * 64 + nt * 16 + (lane & 15);
            float bb = b3[c], sc = s3v[c], tt = t3v[c];
            #pragma unroll
            for (int mt = 0; mt < 4; ++mt)
                #pragma unroll
                for (int r = 0; r < 4; ++r) {
                    int ml = (lane >> 4) * 4 + r;
                    float v = fmaxf(fmaf(acc3[mt][nt][r] + bb, sc, tt), 0.f);
                    x3A[((mt * 8 + (c >> 5)) * 64 + ml + (((c >> 3) & 3) << 4)) * 8 + (c & 7)] = f2bf(v);
                }
        }
    }
    // prefetch L4 (nh=0, kc=0) B-frags
    short8 bb4[2][4];
    #pragma unroll
    for (int t = 0; t < 4; ++t) bb4[0][t] = W4v[(w * 4 + t) * 64 + lane];
    __syncthreads();                         // x3A visible; all x2A reads done

    // ---- L4: 256->512 MFMA, 2 halves x 8 kc, B ping-pong prefetch ----
    #pragma unroll 1
    for (int nh = 0; nh < 2; ++nh) {
        floatx4 acc4[4][4];
        #pragma unroll
        for (int mt = 0; mt < 4; ++mt)
            #pragma unroll
            for (int nt = 0; nt < 4; ++nt) acc4[mt][nt] = (floatx4)0.f;
        #pragma unroll
        for (int kc = 0; kc < 8; ++kc) {
            if (kc < 7) {
                #pragma unroll
                for (int t = 0; t < 4; ++t)
                    bb4[(kc + 1) & 1][t] =
                        W4v[((kc + 1) * 32 + nh * 16 + w * 4 + t) * 64 + lane];
            } else if (nh == 0) {
                #pragma unroll
                for (int t = 0; t < 4; ++t)
                    bb4[0][t] = W4v[(16 + w * 4 + t) * 64 + lane];   // nh1 kc0
            }
            short8 a[4];
            #pragma unroll
            for (int mt = 0; mt < 4; ++mt)
                a[mt] = *reinterpret_cast<const short8*>(x3A + ((mt * 8 + kc) * 64 + lane) * 8);
            #pragma unroll
            for (int nt = 0; nt < 4; ++nt)
                #pragma unroll
                for (int mt = 0; mt < 4; ++mt)
                    acc4[mt][nt] = __builtin_amdgcn_mfma_f32_16x16x32_bf16(
                        a[mt], bb4[kc & 1][nt], acc4[mt][nt], 0, 0, 0);
        }
        // epilogue: two 32-row halves through rep[32][256] (clobbers x2A: its
        // reads ended before the x3A barrier)
        #pragma unroll
        for (int mh = 0; mh < 2; ++mh) {
            #pragma unroll
            for (int nt = 0; nt < 4; ++nt) {
                int cl = w * 64 + nt * 16 + (lane & 15);
                float bb = b4[nh * 256 + cl];
                #pragma unroll
                for (int mt2 = 0; mt2 < 2; ++mt2) {
                    #pragma unroll
                    for (int r = 0; r < 4; ++r) {
                        int ml = mt2 * 16 + (lane >> 4) * 4 + r;
                        rep[ml * 256 + cl] = f2bf(acc4[mh * 2 + mt2][nt][r] + bb);
                    }
                }
            }
            __syncthreads();                 // rep half visible
            #pragma unroll
            for (int r2 = 0; r2 < 4; ++r2) {
                int q = r2 * 256 + tid;      // uint4 index, 0..1023
                int m = q >> 5, co = (q & 31) * 8;
                *reinterpret_cast<uint4*>(
                    &x4out[((size_t)(b * N_ + n0 + mh * 32 + m)) * 512 + nh * 256 + co]) =
                    *reinterpret_cast<const uint4*>(rep + m * 256 + co);
            }
            __syncthreads();                 // rep free for next half
        }
    }
}

// ---------------- per-voxel max-pool + MFMA compression (occupied only) ----
__global__ __launch_bounds__(256) void k_pool(
        const int* __restrict__ head, const int* __restrict__ nxt,
        const unsigned short* __restrict__ x4,
        const unsigned short* __restrict__ WcB, const float* __restrict__ bcv,
        float* __restrict__ out, const int* __restrict__ list,
        const int* __restrict__ cnt)
{
    __shared__ __align__(16) unsigned short mxA[16 * 64 * 8];  // [kc][lane][8] 16KB
    __shared__ float part[4][256];                              // [wave][m*16+c] 4KB
    __shared__ int gidsh[16];
    int tid = threadIdx.x;
    int w = tid >> 6, lane = tid & 63;
    int kh = w >> 1, nt = w & 1;
    int g = tid >> 4, l = tid & 15;          // phase-1: group=voxel slot, lane
    int nocc = cnt[0];

    // preload Wc B-fragments (iteration-invariant): 8 short8 = 32 VGPR
    short8 breg[8];
    #pragma unroll
    for (int kk = 0; kk < 8; ++kk)
        breg[kk] = *reinterpret_cast<const short8*>(
            WcB + (size_t)(((kh * 8 + kk) * 2 + nt) * 64 + lane) * 8);

    for (int base = blockIdx.x * 16; base < nocc; base += 2048 * 16) {
        {   // ---- phase 1: chain walk + max + A-frag repack ----
            float mx[4][8];
            int idx = base + g;
            if (idx < nocc) {
                int gid = list[idx];
                if (l == 0) gidsh[g] = gid;
                #pragma unroll
                for (int i = 0; i < 4; ++i)
                    #pragma unroll
                    for (int j = 0; j < 8; ++j) mx[i][j] = -3.0e38f;
                int cur = head[gid];
                while (cur >= 0) {
                    const uint4* row = reinterpret_cast<const uint4*>(x4 + (size_t)cur * 512);
                    #pragma unroll
                    for (int i = 0; i < 4; ++i) {
                        uint4 r = row[i * 16 + l];     // ch c = i*128 + l*8 + j
                        unsigned rr[4] = {r.x, r.y, r.z, r.w};
                        #pragma unroll
                        for (int q = 0; q < 4; ++q) {
                            mx[i][2*q]   = fmaxf(mx[i][2*q],   __uint_as_float((rr[q] & 0xFFFFu) << 16));
                            mx[i][2*q+1] = fmaxf(mx[i][2*q+1], __uint_as_float(rr[q] & 0xFFFF0000u));
                        }
                    }
                    cur = nxt[cur];
                }
            } else {
                if (l == 0) gidsh[g] = -1;
                #pragma unroll
                for (int i = 0; i < 4; ++i)
                    #pragma unroll
                    for (int j = 0; j < 8; ++j) mx[i][j] = 0.f;
            }
            // repack (lossless: maxes of bf16 are bf16): octet o=i*16+l ->
            // kc = i*4 + (l>>2), hi = l&3, dest lane' = g + hi*16
            #pragma unroll
            for (int i = 0; i < 4; ++i) {
                __align__(16) unsigned short o[8];
                #pragma unroll
                for (int j = 0; j < 8; ++j) o[j] = f2bf(mx[i][j]);
                int kc = i * 4 + (l >> 2);
                int dl = g + ((l & 3) << 4);
                *reinterpret_cast<uint4*>(&mxA[(kc * 64 + dl) * 8]) =
                    *reinterpret_cast<const uint4*>(o);
            }
        }
        __syncthreads();
        {   // ---- phase 2: MFMA 16x32x512 (this wave: 8 k-chunks, 1 n-tile) ----
            floatx4 acc = (floatx4)0.f;
            #pragma unroll
            for (int kk = 0; kk < 8; ++kk) {
                short8 a = *reinterpret_cast<const short8*>(
                    &mxA[((kh * 8 + kk) * 64 + lane) * 8]);
                acc = __builtin_amdgcn_mfma_f32_16x16x32_bf16(a, breg[kk], acc, 0, 0, 0);
            }
            #pragma unroll
            for (int r = 0; r < 4; ++r)
                part[w][((lane >> 4) * 4 + r) * 16 + (lane & 15)] = acc[r];
        }
        __syncthreads();
        {   // ---- phase 2b: cross-wave K-reduce + bias + relu + scatter ----
            int m = tid & 15, n = tid >> 4;          // voxel m, channel n / n+16
            int gid = gidsh[m];
            if (gid >= 0) {
                float v0 = fmaxf(part[0][m * 16 + n] + part[2][m * 16 + n] + bcv[n], 0.f);
                float v1 = fmaxf(part[1][m * 16 + n] + part[3][m * 16 + n] + bcv[n + 16], 0.f);
                int b = gid / HWv, v = gid - b * HWv;
                int x = v / GYv, y = v - x * GYv;
                out[(((size_t)b * NHv + n)      * GXv + x) * GYv + y] = v0;
                out[(((size_t)b * NHv + n + 16) * GXv + x) * GYv + y] = v1;
            }
        }
        __syncthreads();                             // protect gidsh/mxA/part
    }
}

extern "C" void kernel_launch(void* const* d_in, const int* in_sizes, int n_in,
                              void* d_out, int out_size, void* d_ws, size_t ws_size,
                              hipStream_t stream) {
    const float* pt_fea = (const float*)d_in[0];
    const int*   xy     = (const int*)d_in[1];
    const float* s0v = (const float*)d_in[2];  const float* t0v = (const float*)d_in[3];
    const float* s1v = (const float*)d_in[4];  const float* t1v = (const float*)d_in[5];
    const float* s2v = (const float*)d_in[6];  const float* t2v = (const float*)d_in[7];
    const float* s3v = (const float*)d_in[8];  const float* t3v = (const float*)d_in[9];
    const float* W1  = (const float*)d_in[10]; const float* b1  = (const float*)d_in[11];
    const float* W2  = (const float*)d_in[12]; const float* b2  = (const float*)d_in[13];
    const float* W3  = (const float*)d_in[14]; const float* b3  = (const float*)d_in[15];
    const float* W4  = (const float*)d_in[16]; const float* b4  = (const float*)d_in[17];
    const float* Wc  = (const float*)d_in[18]; const float* bc  = (const float*)d_in[19];

    // workspace: x4 | head | nxt | list | cnt | W2B | W3B | W4B | WcB
    char* ws = (char*)d_ws;
    size_t off = 0;
    unsigned short* x4   = (unsigned short*)(ws + off); off += (size_t)B_ * N_ * 512 * 2;
    int* head            = (int*)(ws + off);            off += (size_t)B_ * HWv * 4;
    int* nxt             = (int*)(ws + off);            off += (size_t)B_ * N_ * 4;
    int* list            = (int*)(ws + off);            off += (size_t)B_ * N_ * 4;
    int* cnt             = (int*)(ws + off);            off += 256;
    unsigned short* W2B  = (unsigned short*)(ws + off); off += 64 * 128 * 2;
    unsigned short* W3B  = (unsigned short*)(ws + off); off += 128 * 256 * 2;
    unsigned short* W4B  = (unsigned short*)(ws + off); off += 256 * 512 * 2;
    unsigned short* WcB  = (unsigned short*)(ws + off); off += 512 * 32 * 2;

    hipLaunchKernelGGL(k_init_head, dim3(1350),  dim3(256), 0, stream, head, cnt);
    hipLaunchKernelGGL(k_zero_out,  dim3(10800), dim3(256), 0, stream, (uint4*)d_out);
    hipLaunchKernelGGL(k_chain,     dim3(512),   dim3(256), 0, stream, xy, head, nxt, list, cnt);
    hipLaunchKernelGGL(k_cvtB,      dim3(4),     dim3(256), 0, stream, W2, W2B, 64, 128);
    hipLaunchKernelGGL(k_cvtB,      dim3(16),    dim3(256), 0, stream, W3, W3B, 128, 256);
    hipLaunchKernelGGL(k_cvtB,      dim3(64),    dim3(256), 0, stream, W4, W4B, 256, 512);
    hipLaunchKernelGGL(k_cvtB,      dim3(8),     dim3(256), 0, stream, Wc, WcB, 512, 32);
    hipLaunchKernelGGL(k_mlp,       dim3(2048),  dim3(256), 0, stream,
        pt_fea, s0v, t0v, s1v, t1v, s2v, t2v, s3v, t3v,
        W1, b1, W2B, b2, W3B, b3, W4B, b4, x4);
    hipLaunchKernelGGL(k_pool,      dim3(2048),  dim3(256), 0, stream,
        head, nxt, x4, WcB, bc, (float*)d_out, list, cnt);
}